// Round 2
// baseline (6045.580 us; speedup 1.0000x reference)
//
#include <hip/hip_runtime.h>
#include <math.h>

// Problem constants: B=16, N=512, D=768, Dh=1536, HEADS=3, keys>=384 masked.
// Workspace arena (floats), ~122.2 MB total:
//   [0, 131072)                small scalars / nnz lists
//   [131072, 12713984)         XCAT [8192,1536]  (OUT0 aliases its first 6.29M early)
//   Z = 12713984:              phase-overlaid big region (17,825,792 floats)
//     phase1: AX=Z+0, AXW0=Z+6291456          (XW0 lives in d_out)
//     phase2: CONVE=Z+0
//     phase3: Qh=Z+0, Kh=Z+4194304, P=Z+8388608 (48*512*384)
//     phase4: ADJ2=Z+0
//     phase5: XW1=Z+4194304 (over dead P head), OUTL1=Z+10485760, H1=Z+0

namespace {

constexpr long long SZ_MD  = 8192LL * 768;     // 6291456
constexpr long long SZ_MDH = 8192LL * 1536;    // 12582912

constexpr long long O_DEN    = 0;
constexpr long long O_DEN2   = 8192;
constexpr long long O_SUMS   = 16384;   // 48 doubles (byte offset 65536, 8B aligned)
constexpr long long O_THR    = 16480;
constexpr long long O_MIDX   = 16496;
constexpr long long O_NNZC   = 16512;   // 8192 ints
constexpr long long O_NNZJ   = 24704;   // 8192*4 ints
constexpr long long O_NNZV   = 57472;   // 8192*4 floats

constexpr long long O_XCAT   = 131072;
constexpr long long OZ       = O_XCAT + SZ_MDH;          // 12713984
constexpr long long O_AX     = OZ;
constexpr long long O_AXW0   = OZ + SZ_MD;
constexpr long long O_CONVE  = OZ;
constexpr long long O_QH     = OZ;
constexpr long long O_KH     = OZ + 4194304;
constexpr long long O_P      = OZ + 8388608;             // 48*512*384 = 9437184
constexpr long long O_ADJ2   = OZ;                       // 16*512*512 = 4194304
constexpr long long O_XW1    = OZ + 4194304;
constexpr long long O_OUTL1  = OZ + 10485760;
constexpr long long O_H1     = OZ;
constexpr long long TOTAL_FLOATS = O_P + 9437184;        // 30539776  (~122.2 MB)

__global__ void sentinel_kernel(float* out) {
    if (threadIdx.x == 0 && blockIdx.x == 0) out[0] = 1.0e6f;
}

// ---------------- row sum (+1) ----------------
__global__ void rowsum_kernel(const float* __restrict__ A, float* __restrict__ out, int ncols) {
    const float* row = A + (long long)blockIdx.x * ncols;
    float s = 0.f;
    for (int j = threadIdx.x; j < ncols; j += 256) s += row[j];
    __shared__ float red[256];
    red[threadIdx.x] = s;
    __syncthreads();
    for (int st = 128; st > 0; st >>= 1) {
        if (threadIdx.x < st) red[threadIdx.x] += red[threadIdx.x + st];
        __syncthreads();
    }
    if (threadIdx.x == 0) out[blockIdx.x] = red[0] + 1.0f;
}

// ------------- tiled GEMM: C = (A[M,K] * B[N,K]^T)/divd + bias, opt relu -------------
__global__ void gemm_nt_kernel(const float* __restrict__ A, const float* __restrict__ B,
                               float* __restrict__ C, const float* __restrict__ bias,
                               int M, int N, int K, int lda, int ldb, int ldc,
                               long long sA, long long sB, long long sC,
                               float divd, int relu)
{
    int z = blockIdx.z;
    A += z * sA; B += z * sB; C += z * sC;
    __shared__ float As[64][17];
    __shared__ float Bs[64][17];
    const int tid = threadIdx.x;
    const int tx = tid & 15, ty = tid >> 4;
    const int m0 = blockIdx.y * 64, n0 = blockIdx.x * 64;
    float acc[4][4] = {};
    for (int kt = 0; kt < K; kt += 16) {
        #pragma unroll
        for (int l = 0; l < 4; ++l) {
            int idx = tid + l * 256;
            int r = idx >> 4, c = idx & 15;
            int kk = kt + c;
            int mm = m0 + r;
            As[r][c] = (mm < M && kk < K) ? A[(long long)mm * lda + kk] : 0.f;
            int nn = n0 + r;
            Bs[r][c] = (nn < N && kk < K) ? B[(long long)nn * ldb + kk] : 0.f;
        }
        __syncthreads();
        #pragma unroll
        for (int k2 = 0; k2 < 16; ++k2) {
            float a[4], b[4];
            #pragma unroll
            for (int i = 0; i < 4; ++i) a[i] = As[ty * 4 + i][k2];
            #pragma unroll
            for (int j = 0; j < 4; ++j) b[j] = Bs[tx * 4 + j][k2];
            #pragma unroll
            for (int i = 0; i < 4; ++i)
                #pragma unroll
                for (int j = 0; j < 4; ++j)
                    acc[i][j] += a[i] * b[j];
        }
        __syncthreads();
    }
    #pragma unroll
    for (int i = 0; i < 4; ++i) {
        int mm = m0 + ty * 4 + i;
        if (mm >= M) continue;
        #pragma unroll
        for (int j = 0; j < 4; ++j) {
            int nn = n0 + tx * 4 + j;
            if (nn >= N) continue;
            float v = acc[i][j];
            if (divd != 1.f) v = v / divd;
            if (bias) v += bias[nn];
            if (relu) v = fmaxf(v, 0.f);
            C[(long long)mm * ldc + nn] = v;
        }
    }
}

// ------------- tiled GEMM: C = A[M,K] * B[K,N] (batched) -------------
__global__ void gemm_nn_kernel(const float* __restrict__ A, const float* __restrict__ B,
                               float* __restrict__ C, int M, int N, int K,
                               int lda, int ldb, int ldc,
                               long long sA, long long sB, long long sC)
{
    int z = blockIdx.z;
    A += z * sA; B += z * sB; C += z * sC;
    __shared__ float As[64][17];
    __shared__ float Bs[16][65];
    const int tid = threadIdx.x;
    const int tx = tid & 15, ty = tid >> 4;
    const int m0 = blockIdx.y * 64, n0 = blockIdx.x * 64;
    float acc[4][4] = {};
    for (int kt = 0; kt < K; kt += 16) {
        #pragma unroll
        for (int l = 0; l < 4; ++l) {
            int idx = tid + l * 256;
            int r = idx >> 4, c = idx & 15;
            int mm = m0 + r, kk = kt + c;
            As[r][c] = (mm < M && kk < K) ? A[(long long)mm * lda + kk] : 0.f;
            int rb = idx >> 6, cb = idx & 63;
            int kk2 = kt + rb, nn = n0 + cb;
            Bs[rb][cb] = (kk2 < K && nn < N) ? B[(long long)kk2 * ldb + nn] : 0.f;
        }
        __syncthreads();
        #pragma unroll
        for (int k2 = 0; k2 < 16; ++k2) {
            float a[4], b[4];
            #pragma unroll
            for (int i = 0; i < 4; ++i) a[i] = As[ty * 4 + i][k2];
            #pragma unroll
            for (int j = 0; j < 4; ++j) b[j] = Bs[k2][tx * 4 + j];
            #pragma unroll
            for (int i = 0; i < 4; ++i)
                #pragma unroll
                for (int j = 0; j < 4; ++j)
                    acc[i][j] += a[i] * b[j];
        }
        __syncthreads();
    }
    #pragma unroll
    for (int i = 0; i < 4; ++i) {
        int mm = m0 + ty * 4 + i;
        if (mm >= M) continue;
        #pragma unroll
        for (int j = 0; j < 4; ++j) {
            int nn = n0 + tx * 4 + j;
            if (nn >= N) continue;
            C[(long long)mm * ldc + nn] = acc[i][j];
        }
    }
}

// ------------- Conv1d(N,N,3) as GEMM -------------
// conve[b,o,t] = relu(sum_{i,k} Wc[o*1536 + i*3+k] * X[b,i,t+k] + bias[o]), t in [0,766)
__global__ void conv_gemm_kernel(const float* __restrict__ Wc, const float* __restrict__ X,
                                 const float* __restrict__ bias, float* __restrict__ C)
{
    const int b = blockIdx.z;
    const float* Xb = X + (long long)b * 512 * 768;
    float* Cb = C + (long long)b * 512 * 766;
    __shared__ float As[64][17];
    __shared__ float Bs[16][65];
    const int tid = threadIdx.x;
    const int tx = tid & 15, ty = tid >> 4;
    const int m0 = blockIdx.y * 64, n0 = blockIdx.x * 64;
    float acc[4][4] = {};
    for (int kt = 0; kt < 1536; kt += 16) {
        #pragma unroll
        for (int l = 0; l < 4; ++l) {
            int idx = tid + l * 256;
            int r = idx >> 4, c = idx & 15;
            As[r][c] = Wc[(long long)(m0 + r) * 1536 + kt + c];
            int rb = idx >> 6, cb = idx & 63;
            int kk = kt + rb;
            int ii = kk / 3, k3 = kk - ii * 3;
            int t = n0 + cb;
            Bs[rb][cb] = (t < 766) ? Xb[(long long)ii * 768 + t + k3] : 0.f;
        }
        __syncthreads();
        #pragma unroll
        for (int k2 = 0; k2 < 16; ++k2) {
            float a[4], b2[4];
            #pragma unroll
            for (int i = 0; i < 4; ++i) a[i] = As[ty * 4 + i][k2];
            #pragma unroll
            for (int j = 0; j < 4; ++j) b2[j] = Bs[k2][tx * 4 + j];
            #pragma unroll
            for (int i = 0; i < 4; ++i)
                #pragma unroll
                for (int j = 0; j < 4; ++j)
                    acc[i][j] += a[i] * b2[j];
        }
        __syncthreads();
    }
    #pragma unroll
    for (int i = 0; i < 4; ++i) {
        int mm = m0 + ty * 4 + i;
        float bb = bias[mm];
        #pragma unroll
        for (int j = 0; j < 4; ++j) {
            int nn = n0 + tx * 4 + j;
            if (nn >= 766) continue;
            Cb[(long long)mm * 766 + nn] = fmaxf(acc[i][j] + bb, 0.f);
        }
    }
}

// ------------- GCN layer-0 epilogue: out = relu((axw+b)/denom) + xw + b -------------
__global__ void gcn_epilogue_kernel(const float* __restrict__ axw, const float* __restrict__ xw,
                                    const float* __restrict__ bias, const float* __restrict__ denom,
                                    float* __restrict__ out)
{
    long long idx = (long long)blockIdx.x * 256 + threadIdx.x;  // over 8192*768
    int m = (int)(idx / 768);
    int d = (int)(idx - (long long)m * 768);
    float bb = bias[d];
    float v = (axw[idx] + bb) / denom[m];
    out[idx] = fmaxf(v, 0.f) + xw[idx] + bb;
}

// ------------- copy inputs into xcat[:, 0:768] -------------
__global__ void copy_concat_kernel(const float* __restrict__ inp, float* __restrict__ xcat)
{
    long long idx = (long long)blockIdx.x * 256 + threadIdx.x;  // over 8192*768
    int m = (int)(idx / 768);
    int d = (int)(idx - (long long)m * 768);
    xcat[(long long)m * 1536 + d] = inp[idx];
}

// ------------- row softmax over 384 stored cols (ld=384) -------------
__global__ void softmax_kernel(float* __restrict__ P)
{
    float* row = P + (long long)blockIdx.x * 384;
    const int t = threadIdx.x;  // 128 threads
    float v0 = row[t], v1 = row[t + 128], v2 = row[t + 256];
    float m = fmaxf(v0, fmaxf(v1, v2));
    #pragma unroll
    for (int off = 32; off > 0; off >>= 1) m = fmaxf(m, __shfl_down(m, off));
    __shared__ float redm[2];
    if ((t & 63) == 0) redm[t >> 6] = m;
    __syncthreads();
    m = fmaxf(redm[0], redm[1]);
    float e0 = expf(v0 - m), e1 = expf(v1 - m), e2 = expf(v2 - m);
    float s = e0 + e1 + e2;
    #pragma unroll
    for (int off = 32; off > 0; off >>= 1) s += __shfl_down(s, off);
    __shared__ float reds[2];
    if ((t & 63) == 0) reds[t >> 6] = s;
    __syncthreads();
    s = reds[0] + reds[1];
    row[t] = e0 / s;
    row[t + 128] = e1 / s;
    row[t + 256] = e2 / s;
}

// ------------- sums[bh] = sum of p_attn[bh] (f64 accumulate), 196608 entries -------------
__global__ void sums_kernel(const float* __restrict__ P, double* __restrict__ sums)
{
    const float* p = P + (long long)blockIdx.x * 196608;
    double s = 0.0;
    for (int i = threadIdx.x; i < 196608; i += 256) s += (double)p[i];
    __shared__ double red[256];
    red[threadIdx.x] = s;
    __syncthreads();
    for (int st = 128; st > 0; st >>= 1) {
        if (threadIdx.x < st) red[threadIdx.x] += red[threadIdx.x + st];
        __syncthreads();
    }
    if (threadIdx.x == 0) sums[blockIdx.x] = red[0];
}

// ------------- prob = softmax(sums, axis=batch); maxidx[b] = first-argmax_h -------------
__global__ void decide_kernel(const double* __restrict__ sums, int* __restrict__ maxidx)
{
    if (threadIdx.x != 0 || blockIdx.x != 0) return;
    float s[16][3], prob[16][3];
    for (int b = 0; b < 16; ++b)
        for (int h = 0; h < 3; ++h) s[b][h] = (float)sums[b * 3 + h];
    for (int h = 0; h < 3; ++h) {
        float m = -1e30f;
        for (int b = 0; b < 16; ++b) m = fmaxf(m, s[b][h]);
        float e[16]; float Z = 0.f;
        for (int b = 0; b < 16; ++b) { e[b] = expf(s[b][h] - m); Z += e[b]; }
        for (int b = 0; b < 16; ++b) prob[b][h] = e[b] / Z;
    }
    for (int b = 0; b < 16; ++b) {
        int best = 0; float bv = prob[b][0];
        for (int h = 1; h < 3; ++h) if (prob[b][h] > bv) { bv = prob[b][h]; best = h; }
        maxidx[b] = best;
    }
}

// ------------- thr[b] = 2nd largest of selected head's p (196608 entries) -------------
__global__ void top2_kernel(const float* __restrict__ P, const int* __restrict__ maxidx,
                            float* __restrict__ thr)
{
    int b = blockIdx.x;
    const float* p = P + ((long long)b * 3 + maxidx[b]) * 196608;
    float m1 = -1e30f, m2 = -1e30f;
    for (int i = threadIdx.x; i < 196608; i += 256) {
        float v = p[i];
        if (v > m1) { m2 = m1; m1 = v; }
        else if (v > m2) { m2 = v; }
    }
    __shared__ float r1[256], r2[256];
    r1[threadIdx.x] = m1; r2[threadIdx.x] = m2;
    __syncthreads();
    if (threadIdx.x == 0) {
        float M1 = -1e30f, M2 = -1e30f;
        for (int i = 0; i < 256; ++i) {
            float a = r1[i], c = r2[i];
            if (a > M1) { M2 = M1; M1 = a; } else if (a > M2) { M2 = a; }
            if (c > M1) { M2 = M1; M1 = c; } else if (c > M2) { M2 = c; }
        }
        thr[b] = M2;
    }
}

// ------------- adj2 dense build: 16*512*512; P has ld=384 (cols>=384 are 0) -------------
__global__ void adj2_kernel(const float* __restrict__ P, const int* __restrict__ maxidx,
                            const float* __restrict__ thr, float* __restrict__ adj2)
{
    long long idx = (long long)blockIdx.x * 256 + threadIdx.x;  // 16*512*512
    int b = (int)(idx >> 18);
    long long rem = idx & 262143;
    int i = (int)(rem >> 9), j = (int)(rem & 511);
    const float* p = P + ((long long)b * 3 + maxidx[b]) * 196608;
    float t = thr[b];
    float bij = (j < 384 && p[(long long)i * 384 + j] >= t) ? 1.f : 0.f;
    float out;
    if (i == j) out = bij;
    else {
        float bji = (i < 384 && p[(long long)j * 384 + i] >= t) ? 1.f : 0.f;
        out = (bij != 0.f) ? (1.f + bji) : 0.f;
    }
    adj2[idx] = out;
}

// ------------- extract nnz (<=4/row) + denom2 -------------
__global__ void extract_nnz_kernel(const float* __restrict__ adj2, int* __restrict__ cnt,
                                   int* __restrict__ jn, float* __restrict__ jv,
                                   float* __restrict__ den2)
{
    int r = blockIdx.x * 256 + threadIdx.x;  // 0..8191
    if (r >= 8192) return;
    int b = r >> 9;
    const float* row = adj2 + (long long)r * 512;
    int c = 0; float s = 0.f;
    for (int j = 0; j < 512; ++j) {
        float a = row[j];
        if (a != 0.f) {
            s += a;
            if (c < 4) { jn[r * 4 + c] = b * 512 + j; jv[r * 4 + c] = a; }
            c++;
        }
    }
    cnt[r] = c < 4 ? c : 4;
    den2[r] = s + 1.f;
}

// ------------- GCN layer-1 fused sparse epilogue -------------
// out[m,d] = relu((sum_s v_s*XW1[j_s,d] + b1[d])/den2[m]) + XW1[m,d] + b1[d]
__global__ void gcn1_epilogue_kernel(const float* __restrict__ XW1, const float* __restrict__ b1,
                                     const float* __restrict__ den2, const int* __restrict__ cnt,
                                     const int* __restrict__ jn, const float* __restrict__ jv,
                                     float* __restrict__ out)
{
    int m = blockIdx.x;            // 8192 rows
    int c = cnt[m];
    float d2 = den2[m];
    int js[4]; float vs[4];
    for (int s = 0; s < c; ++s) { js[s] = jn[m * 4 + s]; vs[s] = jv[m * 4 + s]; }
    const float* xrow = XW1 + (long long)m * 768;
    float* orow = out + (long long)m * 768;
    #pragma unroll
    for (int l = 0; l < 3; ++l) {
        int d = threadIdx.x + l * 256;
        float ax = 0.f;
        for (int s = 0; s < c; ++s) ax += vs[s] * XW1[(long long)js[s] * 768 + d];
        float bb = b1[d];
        float v = (ax + bb) / d2;
        orow[d] = fmaxf(v, 0.f) + xrow[d] + bb;
    }
}

}  // namespace

extern "C" void kernel_launch(void* const* d_in, const int* in_sizes, int n_in,
                              void* d_out, int out_size, void* d_ws, size_t ws_size,
                              hipStream_t stream) {
    const float* adj = (const float*)d_in[0];
    const float* inp = (const float*)d_in[1];
    // d_in[2] = score_mask: fixed function of indices (key>=384) — never read.
    const float* W0w = (const float*)d_in[3];
    const float* W0b = (const float*)d_in[4];
    const float* W1w = (const float*)d_in[5];
    const float* W1b = (const float*)d_in[6];
    const float* Cw  = (const float*)d_in[7];
    const float* Cbi = (const float*)d_in[8];
    const float* Lw  = (const float*)d_in[9];
    const float* Lb  = (const float*)d_in[10];
    const float* F1  = (const float*)d_in[11];
    const float* F2  = (const float*)d_in[12];
    const float* Qw  = (const float*)d_in[13];
    const float* Qb  = (const float*)d_in[14];
    const float* Kw  = (const float*)d_in[15];
    const float* Kbi = (const float*)d_in[16];
    float* out = (float*)d_out;

    if (ws_size < (size_t)TOTAL_FLOATS * sizeof(float)) {
        // distinguishable failure signature: absmax ~1e6 => workspace too small
        sentinel_kernel<<<dim3(1), dim3(64), 0, stream>>>(out);
        return;
    }

    float* W = (float*)d_ws;
    float*  DEN   = W + O_DEN;
    float*  DEN2  = W + O_DEN2;
    double* SUMS  = (double*)(W + O_SUMS);
    float*  THR   = W + O_THR;
    int*    MIDX  = (int*)(W + O_MIDX);
    int*    NNZC  = (int*)(W + O_NNZC);
    int*    NNZJ  = (int*)(W + O_NNZJ);
    float*  NNZV  = W + O_NNZV;
    float*  XCAT  = W + O_XCAT;
    float*  AX    = W + O_AX;
    float*  AXW0  = W + O_AXW0;
    float*  OUT0  = XCAT;          // aliases XCAT region, dead before XCAT written
    float*  CONVE = W + O_CONVE;
    float*  QH    = W + O_QH;
    float*  KH    = W + O_KH;
    float*  P     = W + O_P;
    float*  ADJ2  = W + O_ADJ2;
    float*  XW1   = W + O_XW1;
    float*  OUTL1 = W + O_OUTL1;
    float*  H1    = W + O_H1;
    float*  XW0   = out;           // d_out as scratch; fully overwritten at the end

    const float divs = sqrtf(512.0f);

    // ---- GCN layer 0 ----
    rowsum_kernel<<<dim3(8192), dim3(256), 0, stream>>>(adj, DEN, 512);
    gemm_nn_kernel<<<dim3(12, 8, 16), dim3(256), 0, stream>>>(
        adj, inp, AX, 512, 768, 512, 512, 768, 768, 262144LL, 393216LL, 393216LL);
    gemm_nt_kernel<<<dim3(12, 128, 1), dim3(256), 0, stream>>>(
        inp, W0w, XW0, nullptr, 8192, 768, 768, 768, 768, 768, 0, 0, 0, 1.f, 0);
    gemm_nt_kernel<<<dim3(12, 128, 1), dim3(256), 0, stream>>>(
        AX, W0w, AXW0, nullptr, 8192, 768, 768, 768, 768, 768, 0, 0, 0, 1.f, 0);
    gcn_epilogue_kernel<<<dim3(24576), dim3(256), 0, stream>>>(AXW0, XW0, W0b, DEN, OUT0);

    // ---- conv + linearc -> xcat ----
    conv_gemm_kernel<<<dim3(12, 8, 16), dim3(256), 0, stream>>>(Cw, OUT0, Cbi, CONVE);
    gemm_nt_kernel<<<dim3(12, 128, 1), dim3(256), 0, stream>>>(
        CONVE, Lw, XCAT + 768, Lb, 8192, 768, 766, 766, 766, 1536, 0, 0, 0, 1.f, 0);
    copy_concat_kernel<<<dim3(24576), dim3(256), 0, stream>>>(inp, XCAT);

    // ---- attention scores per head ----
    for (int h = 0; h < 3; ++h) {
        gemm_nt_kernel<<<dim3(8, 128, 1), dim3(256), 0, stream>>>(
            XCAT, Qw + (long long)h * 512 * 1536, QH, Qb + h * 512,
            8192, 512, 1536, 1536, 1536, 512, 0, 0, 0, 1.f, 0);
        gemm_nt_kernel<<<dim3(8, 128, 1), dim3(256), 0, stream>>>(
            XCAT, Kw + (long long)h * 512 * 1536, KH, Kbi + h * 512,
            8192, 512, 1536, 1536, 1536, 512, 0, 0, 0, 1.f, 0);
        gemm_nt_kernel<<<dim3(6, 8, 16), dim3(256), 0, stream>>>(
            QH, KH, P + (long long)h * 196608, nullptr,
            512, 384, 512, 512, 512, 384, 262144LL, 262144LL, 589824LL, divs, 0);
    }

    // ---- softmax + decisions ----
    softmax_kernel<<<dim3(24576), dim3(128), 0, stream>>>(P);
    sums_kernel<<<dim3(48), dim3(256), 0, stream>>>(P, SUMS);
    decide_kernel<<<dim3(1), dim3(64), 0, stream>>>(SUMS, MIDX);
    top2_kernel<<<dim3(16), dim3(256), 0, stream>>>(P, MIDX, THR);
    adj2_kernel<<<dim3(16384), dim3(256), 0, stream>>>(P, MIDX, THR, ADJ2);
    extract_nnz_kernel<<<dim3(32), dim3(256), 0, stream>>>(ADJ2, NNZC, NNZJ, NNZV, DEN2);

    // ---- GCN layer 1 (sparse adj2) + fc ----
    gemm_nt_kernel<<<dim3(12, 128, 1), dim3(256), 0, stream>>>(
        XCAT, W1w, XW1, nullptr, 8192, 768, 1536, 1536, 1536, 768, 0, 0, 0, 1.f, 0);
    gcn1_epilogue_kernel<<<dim3(8192), dim3(256), 0, stream>>>(XW1, W1b, DEN2, NNZC, NNZJ, NNZV, OUTL1);
    gemm_nt_kernel<<<dim3(12, 128, 1), dim3(256), 0, stream>>>(
        OUTL1, F1, H1, nullptr, 8192, 768, 768, 768, 768, 768, 0, 0, 0, 1.f, 1);
    gemm_nt_kernel<<<dim3(12, 128, 1), dim3(256), 0, stream>>>(
        H1, F2, out, nullptr, 8192, 768, 768, 768, 768, 768, 0, 0, 0, 1.f, 0);
}

// Round 4
// 2405.920 us; speedup vs baseline: 2.5128x; 2.5128x over previous
//
#include <hip/hip_runtime.h>
#include <math.h>

// Problem constants: B=16, N=512, D=768, Dh=1536, HEADS=3, keys>=384 masked.
// All big GEMMs: 128x128x32 MFMA tiles, bf16x2 split (3-pass), fp32 accumulate.
// Workspace arena (floats), ~122.2 MB total:
//   [0, 131072)                small scalars / nnz lists
//   [131072, 12713984)         XCAT [8192,1536]  (OUT0 aliases its first 6.29M early)
//   Z = 12713984:              phase-overlaid big region (17,825,792 floats)
//     phase1: AX=Z+0, AXW0=Z+6291456          (XW0 lives in d_out)
//     phase2: CONVE=Z+0 (ld 768, cols 766..767 zero), LWP=Z+8388608 (768x768)
//             !! LWP must be written AFTER AXW0 is dead (pad_lw launched after
//             !! gcn_epilogue) — round-3 bug was LWP inside live AXW0.
//     phase3: QH=Z+0, KH=Z+4194304, P=Z+8388608 (48*512*384, clobbers dead LWP)
//     phase4: ADJ2=Z+0
//     phase5: XW1=Z+4194304 (over dead KH/P-head), OUTL1=Z+10485760, H1=Z+0

namespace {

constexpr long long SZ_MD  = 8192LL * 768;     // 6291456
constexpr long long SZ_MDH = 8192LL * 1536;    // 12582912

constexpr long long O_DEN    = 0;
constexpr long long O_DEN2   = 8192;
constexpr long long O_SUMS   = 16384;   // 48 doubles
constexpr long long O_THR    = 16480;
constexpr long long O_MIDX   = 16496;
constexpr long long O_NNZC   = 16512;   // 8192 ints
constexpr long long O_NNZJ   = 24704;   // 8192*4 ints
constexpr long long O_NNZV   = 57472;   // 8192*4 floats

constexpr long long O_XCAT   = 131072;
constexpr long long OZ       = O_XCAT + SZ_MDH;          // 12713984
constexpr long long O_AX     = OZ;
constexpr long long O_AXW0   = OZ + SZ_MD;
constexpr long long O_CONVE  = OZ;                       // ld 768
constexpr long long O_LWP    = OZ + 8388608;             // inside future-P, dead AXW0-free window
constexpr long long O_QH     = OZ;
constexpr long long O_KH     = OZ + 4194304;
constexpr long long O_P      = OZ + 8388608;             // 48*512*384 = 9437184
constexpr long long O_ADJ2   = OZ;                       // 16*512*512
constexpr long long O_XW1    = OZ + 4194304;
constexpr long long O_OUTL1  = OZ + 10485760;
constexpr long long O_H1     = OZ;
constexpr long long TOTAL_FLOATS = O_P + 9437184;        // 30539776 (~122.2 MB)

typedef short bf16x8 __attribute__((ext_vector_type(8)));
typedef float f32x4 __attribute__((ext_vector_type(4)));

__global__ void sentinel_kernel(float* out) {
    if (threadIdx.x == 0 && blockIdx.x == 0) out[0] = 1.0e6f;
}

// RNE f32 -> bf16 hi + bf16(residual)
__device__ __forceinline__ void cvt_split(float f, unsigned short& h, unsigned short& l) {
    union { float x; unsigned u; } a; a.x = f;
    unsigned hb = (a.u + 0x7FFFu + ((a.u >> 16) & 1u)) & 0xFFFF0000u;
    h = (unsigned short)(hb >> 16);
    union { unsigned u; float x; } b; b.u = hb;
    float r = f - b.x;
    union { float x; unsigned u; } c; c.x = r;
    l = (unsigned short)((c.u + 0x7FFFu + ((c.u >> 16) & 1u)) >> 16);
}

// ================= MFMA GEMM: C[M,N] = op(A,B)/divd + bias, opt relu ==================
// A[M,K] row-major always. mode 0: Bt[n][k] = B[n*ldb+k] (NT)
//                          mode 1: Bt[n][k] = B[k*ldb+n] (NN)
//                          mode 2: Bt[n][k] = B[(k/3)*768 + n + k%3] (conv window), bias[m],
//                                  cols n>=Nreal zeroed.
// M % 128 == 0, N % 128 == 0 (padded), K % 32 == 0. Grid: (N/128, M/128, z).
__global__ __launch_bounds__(256)
void gemm_mfma_kernel(const float* __restrict__ A, const float* __restrict__ B,
                      float* __restrict__ C, const float* __restrict__ bias,
                      int M, int N, int K, int lda, int ldb, int ldc,
                      long long sA, long long sB, long long sC,
                      float divd, int relu, int mode, int Nreal)
{
    __shared__ __align__(16) unsigned short AhS[4][128][8];
    __shared__ __align__(16) unsigned short AlS[4][128][8];
    __shared__ __align__(16) unsigned short BhS[4][128][8];
    __shared__ __align__(16) unsigned short BlS[4][128][8];

    const int z = blockIdx.z;
    A += z * sA; B += z * sB; C += z * sC;
    const int tid = threadIdx.x;
    const int m0 = blockIdx.y * 128, n0 = blockIdx.x * 128;
    const int lane = tid & 63, wave = tid >> 6;
    const int wm = (wave & 1) * 64, wn = (wave >> 1) * 64;
    const int lkh = lane >> 4, lm = lane & 15;

    f32x4 acc[4][4];
    #pragma unroll
    for (int i = 0; i < 4; ++i)
        #pragma unroll
        for (int j = 0; j < 4; ++j) acc[i][j] = (f32x4){0.f, 0.f, 0.f, 0.f};

    const int achunk = tid & 7, arow0 = tid >> 3;   // A / NT-B staging: 8 k-chunks x 32 rows
    const int bnc = tid & 31, bkr = tid >> 5;       // NN/conv B staging: 32 n-chunks x 8 k

    for (int k0 = 0; k0 < K; k0 += 32) {
        // ---- stage A ----
        {
            const int kl = achunk * 4;
            const int kh = kl >> 3, kp = kl & 7;
            #pragma unroll
            for (int r = 0; r < 4; ++r) {
                const int row = arow0 + r * 32;
                const float4 v = *(const float4*)(A + (long long)(m0 + row) * lda + (k0 + kl));
                unsigned short h0,h1,h2,h3,l0,l1,l2,l3;
                cvt_split(v.x,h0,l0); cvt_split(v.y,h1,l1);
                cvt_split(v.z,h2,l2); cvt_split(v.w,h3,l3);
                uint2 hp, lp;
                hp.x = (unsigned)h0 | ((unsigned)h1 << 16);
                hp.y = (unsigned)h2 | ((unsigned)h3 << 16);
                lp.x = (unsigned)l0 | ((unsigned)l1 << 16);
                lp.y = (unsigned)l2 | ((unsigned)l3 << 16);
                *(uint2*)&AhS[kh][row][kp] = hp;
                *(uint2*)&AlS[kh][row][kp] = lp;
            }
        }
        // ---- stage B ----
        if (mode == 0) {
            const int kl = achunk * 4;
            const int kh = kl >> 3, kp = kl & 7;
            #pragma unroll
            for (int r = 0; r < 4; ++r) {
                const int row = arow0 + r * 32;
                const float4 v = *(const float4*)(B + (long long)(n0 + row) * ldb + (k0 + kl));
                unsigned short h0,h1,h2,h3,l0,l1,l2,l3;
                cvt_split(v.x,h0,l0); cvt_split(v.y,h1,l1);
                cvt_split(v.z,h2,l2); cvt_split(v.w,h3,l3);
                uint2 hp, lp;
                hp.x = (unsigned)h0 | ((unsigned)h1 << 16);
                hp.y = (unsigned)h2 | ((unsigned)h3 << 16);
                lp.x = (unsigned)l0 | ((unsigned)l1 << 16);
                lp.y = (unsigned)l2 | ((unsigned)l3 << 16);
                *(uint2*)&BhS[kh][row][kp] = hp;
                *(uint2*)&BlS[kh][row][kp] = lp;
            }
        } else {
            #pragma unroll
            for (int r = 0; r < 4; ++r) {
                const int k = bkr + r * 8;
                const int kg = k0 + k;
                float vv[4];
                if (mode == 1) {
                    const float4 t = *(const float4*)(B + (long long)kg * ldb + (n0 + bnc * 4));
                    vv[0] = t.x; vv[1] = t.y; vv[2] = t.z; vv[3] = t.w;
                } else {
                    const int ii = kg / 3, k3 = kg - ii * 3;
                    const float* src = B + (long long)ii * 768 + (n0 + bnc * 4) + k3;
                    vv[0] = src[0]; vv[1] = src[1]; vv[2] = src[2]; vv[3] = src[3];
                }
                const int kh = k >> 3, kp = k & 7;
                #pragma unroll
                for (int q = 0; q < 4; ++q) {
                    unsigned short h, l;
                    cvt_split(vv[q], h, l);
                    BhS[kh][bnc * 4 + q][kp] = h;
                    BlS[kh][bnc * 4 + q][kp] = l;
                }
            }
        }
        __syncthreads();
        // ---- fragments + 3-pass MFMA ----
        bf16x8 ah[4], al[4], bh[4], bl[4];
        #pragma unroll
        for (int i = 0; i < 4; ++i) {
            ah[i] = *(const bf16x8*)&AhS[lkh][wm + i * 16 + lm][0];
            al[i] = *(const bf16x8*)&AlS[lkh][wm + i * 16 + lm][0];
        }
        #pragma unroll
        for (int j = 0; j < 4; ++j) {
            bh[j] = *(const bf16x8*)&BhS[lkh][wn + j * 16 + lm][0];
            bl[j] = *(const bf16x8*)&BlS[lkh][wn + j * 16 + lm][0];
        }
        #pragma unroll
        for (int i = 0; i < 4; ++i)
            #pragma unroll
            for (int j = 0; j < 4; ++j) {
                acc[i][j] = __builtin_amdgcn_mfma_f32_16x16x32_bf16(ah[i], bh[j], acc[i][j], 0, 0, 0);
                acc[i][j] = __builtin_amdgcn_mfma_f32_16x16x32_bf16(ah[i], bl[j], acc[i][j], 0, 0, 0);
                acc[i][j] = __builtin_amdgcn_mfma_f32_16x16x32_bf16(al[i], bh[j], acc[i][j], 0, 0, 0);
            }
        __syncthreads();
    }
    // ---- epilogue: C/D layout col=lane&15, row=(lane>>4)*4+reg ----
    const int erow = (lane >> 4) * 4;
    #pragma unroll
    for (int i = 0; i < 4; ++i) {
        #pragma unroll
        for (int reg = 0; reg < 4; ++reg) {
            const int m = m0 + wm + i * 16 + erow + reg;
            #pragma unroll
            for (int j = 0; j < 4; ++j) {
                const int n = n0 + wn + j * 16 + lm;
                float v = acc[i][j][reg];
                if (divd != 1.f) v = v / divd;
                if (bias) v += bias[mode == 2 ? m : n];
                if (relu) v = fmaxf(v, 0.f);
                if (mode == 2 && n >= Nreal) v = 0.f;
                C[(long long)m * ldc + n] = v;
            }
        }
    }
}

// ---------------- row sum (+1) ----------------
__global__ void rowsum_kernel(const float* __restrict__ A, float* __restrict__ out, int ncols) {
    const float* row = A + (long long)blockIdx.x * ncols;
    float s = 0.f;
    for (int j = threadIdx.x; j < ncols; j += 256) s += row[j];
    __shared__ float red[256];
    red[threadIdx.x] = s;
    __syncthreads();
    for (int st = 128; st > 0; st >>= 1) {
        if (threadIdx.x < st) red[threadIdx.x] += red[threadIdx.x + st];
        __syncthreads();
    }
    if (threadIdx.x == 0) out[blockIdx.x] = red[0] + 1.0f;
}

// ---------------- pad linearc_w [768,766] -> [768,768] with zeros ----------------
__global__ void pad_lw_kernel(const float* __restrict__ Lw, float* __restrict__ Lp) {
    int idx = blockIdx.x * 256 + threadIdx.x;  // 589824
    int n = idx / 768, k = idx - n * 768;
    Lp[idx] = (k < 766) ? Lw[n * 766 + k] : 0.f;
}

// ------------- GCN layer-0 epilogue: out = relu((axw+b)/denom) + xw + b -------------
__global__ void gcn_epilogue_kernel(const float* __restrict__ axw, const float* __restrict__ xw,
                                    const float* __restrict__ bias, const float* __restrict__ denom,
                                    float* __restrict__ out)
{
    long long idx = (long long)blockIdx.x * 256 + threadIdx.x;  // over 8192*768
    int m = (int)(idx / 768);
    int d = (int)(idx - (long long)m * 768);
    float bb = bias[d];
    float v = (axw[idx] + bb) / denom[m];
    out[idx] = fmaxf(v, 0.f) + xw[idx] + bb;
}

// ------------- copy inputs into xcat[:, 0:768] -------------
__global__ void copy_concat_kernel(const float* __restrict__ inp, float* __restrict__ xcat)
{
    long long idx = (long long)blockIdx.x * 256 + threadIdx.x;  // over 8192*768
    int m = (int)(idx / 768);
    int d = (int)(idx - (long long)m * 768);
    xcat[(long long)m * 1536 + d] = inp[idx];
}

// ------------- row softmax over 384 stored cols (ld=384) -------------
__global__ void softmax_kernel(float* __restrict__ P)
{
    float* row = P + (long long)blockIdx.x * 384;
    const int t = threadIdx.x;  // 128 threads
    float v0 = row[t], v1 = row[t + 128], v2 = row[t + 256];
    float m = fmaxf(v0, fmaxf(v1, v2));
    #pragma unroll
    for (int off = 32; off > 0; off >>= 1) m = fmaxf(m, __shfl_down(m, off));
    __shared__ float redm[2];
    if ((t & 63) == 0) redm[t >> 6] = m;
    __syncthreads();
    m = fmaxf(redm[0], redm[1]);
    float e0 = expf(v0 - m), e1 = expf(v1 - m), e2 = expf(v2 - m);
    float s = e0 + e1 + e2;
    #pragma unroll
    for (int off = 32; off > 0; off >>= 1) s += __shfl_down(s, off);
    __shared__ float reds[2];
    if ((t & 63) == 0) reds[t >> 6] = s;
    __syncthreads();
    s = reds[0] + reds[1];
    row[t] = e0 / s;
    row[t + 128] = e1 / s;
    row[t + 256] = e2 / s;
}

// ------------- sums[bh] = sum of p_attn[bh] (f64 accumulate), 196608 entries -------------
__global__ void sums_kernel(const float* __restrict__ P, double* __restrict__ sums)
{
    const float* p = P + (long long)blockIdx.x * 196608;
    double s = 0.0;
    for (int i = threadIdx.x; i < 196608; i += 256) s += (double)p[i];
    __shared__ double red[256];
    red[threadIdx.x] = s;
    __syncthreads();
    for (int st = 128; st > 0; st >>= 1) {
        if (threadIdx.x < st) red[threadIdx.x] += red[threadIdx.x + st];
        __syncthreads();
    }
    if (threadIdx.x == 0) sums[blockIdx.x] = red[0];
}

// ------------- prob = softmax(sums, axis=batch); maxidx[b] = first-argmax_h -------------
__global__ void decide_kernel(const double* __restrict__ sums, int* __restrict__ maxidx)
{
    if (threadIdx.x != 0 || blockIdx.x != 0) return;
    float s[16][3], prob[16][3];
    for (int b = 0; b < 16; ++b)
        for (int h = 0; h < 3; ++h) s[b][h] = (float)sums[b * 3 + h];
    for (int h = 0; h < 3; ++h) {
        float m = -1e30f;
        for (int b = 0; b < 16; ++b) m = fmaxf(m, s[b][h]);
        float e[16]; float Z = 0.f;
        for (int b = 0; b < 16; ++b) { e[b] = expf(s[b][h] - m); Z += e[b]; }
        for (int b = 0; b < 16; ++b) prob[b][h] = e[b] / Z;
    }
    for (int b = 0; b < 16; ++b) {
        int best = 0; float bv = prob[b][0];
        for (int h = 1; h < 3; ++h) if (prob[b][h] > bv) { bv = prob[b][h]; best = h; }
        maxidx[b] = best;
    }
}

// ------------- thr[b] = 2nd largest of selected head's p (196608 entries) -------------
__global__ void top2_kernel(const float* __restrict__ P, const int* __restrict__ maxidx,
                            float* __restrict__ thr)
{
    int b = blockIdx.x;
    const float* p = P + ((long long)b * 3 + maxidx[b]) * 196608;
    float m1 = -1e30f, m2 = -1e30f;
    for (int i = threadIdx.x; i < 196608; i += 256) {
        float v = p[i];
        if (v > m1) { m2 = m1; m1 = v; }
        else if (v > m2) { m2 = v; }
    }
    __shared__ float r1[256], r2[256];
    r1[threadIdx.x] = m1; r2[threadIdx.x] = m2;
    __syncthreads();
    if (threadIdx.x == 0) {
        float M1 = -1e30f, M2 = -1e30f;
        for (int i = 0; i < 256; ++i) {
            float a = r1[i], c = r2[i];
            if (a > M1) { M2 = M1; M1 = a; } else if (a > M2) { M2 = a; }
            if (c > M1) { M2 = M1; M1 = c; } else if (c > M2) { M2 = c; }
        }
        thr[b] = M2;
    }
}

// ------------- adj2 dense build: 16*512*512; P has ld=384 (cols>=384 are 0) -------------
__global__ void adj2_kernel(const float* __restrict__ P, const int* __restrict__ maxidx,
                            const float* __restrict__ thr, float* __restrict__ adj2)
{
    long long idx = (long long)blockIdx.x * 256 + threadIdx.x;  // 16*512*512
    int b = (int)(idx >> 18);
    long long rem = idx & 262143;
    int i = (int)(rem >> 9), j = (int)(rem & 511);
    const float* p = P + ((long long)b * 3 + maxidx[b]) * 196608;
    float t = thr[b];
    float bij = (j < 384 && p[(long long)i * 384 + j] >= t) ? 1.f : 0.f;
    float out;
    if (i == j) out = bij;
    else {
        float bji = (i < 384 && p[(long long)j * 384 + i] >= t) ? 1.f : 0.f;
        out = (bij != 0.f) ? (1.f + bji) : 0.f;
    }
    adj2[idx] = out;
}

// ------------- extract nnz (<=4/row) + denom2 -------------
__global__ void extract_nnz_kernel(const float* __restrict__ adj2, int* __restrict__ cnt,
                                   int* __restrict__ jn, float* __restrict__ jv,
                                   float* __restrict__ den2)
{
    int r = blockIdx.x * 256 + threadIdx.x;  // 0..8191
    if (r >= 8192) return;
    int b = r >> 9;
    const float* row = adj2 + (long long)r * 512;
    int c = 0; float s = 0.f;
    for (int j = 0; j < 512; ++j) {
        float a = row[j];
        if (a != 0.f) {
            s += a;
            if (c < 4) { jn[r * 4 + c] = b * 512 + j; jv[r * 4 + c] = a; }
            c++;
        }
    }
    cnt[r] = c < 4 ? c : 4;
    den2[r] = s + 1.f;
}

// ------------- GCN layer-1 fused sparse epilogue -------------
__global__ void gcn1_epilogue_kernel(const float* __restrict__ XW1, const float* __restrict__ b1,
                                     const float* __restrict__ den2, const int* __restrict__ cnt,
                                     const int* __restrict__ jn, const float* __restrict__ jv,
                                     float* __restrict__ out)
{
    int m = blockIdx.x;            // 8192 rows
    int c = cnt[m];
    float d2 = den2[m];
    int js[4]; float vs[4];
    for (int s = 0; s < c; ++s) { js[s] = jn[m * 4 + s]; vs[s] = jv[m * 4 + s]; }
    const float* xrow = XW1 + (long long)m * 768;
    float* orow = out + (long long)m * 768;
    #pragma unroll
    for (int l = 0; l < 3; ++l) {
        int d = threadIdx.x + l * 256;
        float ax = 0.f;
        for (int s = 0; s < c; ++s) ax += vs[s] * XW1[(long long)js[s] * 768 + d];
        float bb = b1[d];
        float v = (ax + bb) / d2;
        orow[d] = fmaxf(v, 0.f) + xrow[d] + bb;
    }
}

}  // namespace

extern "C" void kernel_launch(void* const* d_in, const int* in_sizes, int n_in,
                              void* d_out, int out_size, void* d_ws, size_t ws_size,
                              hipStream_t stream) {
    const float* adj = (const float*)d_in[0];
    const float* inp = (const float*)d_in[1];
    // d_in[2] = score_mask: fixed function of indices (key>=384) — never read.
    const float* W0w = (const float*)d_in[3];
    const float* W0b = (const float*)d_in[4];
    const float* W1w = (const float*)d_in[5];
    const float* W1b = (const float*)d_in[6];
    const float* Cw  = (const float*)d_in[7];
    const float* Cbi = (const float*)d_in[8];
    const float* Lw  = (const float*)d_in[9];
    const float* Lb  = (const float*)d_in[10];
    const float* F1  = (const float*)d_in[11];
    const float* F2  = (const float*)d_in[12];
    const float* Qw  = (const float*)d_in[13];
    const float* Qb  = (const float*)d_in[14];
    const float* Kw  = (const float*)d_in[15];
    const float* Kbi = (const float*)d_in[16];
    float* out = (float*)d_out;

    if (ws_size < (size_t)TOTAL_FLOATS * sizeof(float)) {
        sentinel_kernel<<<dim3(1), dim3(64), 0, stream>>>(out);
        return;
    }

    float* W = (float*)d_ws;
    float*  DEN   = W + O_DEN;
    float*  DEN2  = W + O_DEN2;
    double* SUMS  = (double*)(W + O_SUMS);
    float*  THR   = W + O_THR;
    int*    MIDX  = (int*)(W + O_MIDX);
    int*    NNZC  = (int*)(W + O_NNZC);
    int*    NNZJ  = (int*)(W + O_NNZJ);
    float*  NNZV  = W + O_NNZV;
    float*  XCAT  = W + O_XCAT;
    float*  AX    = W + O_AX;
    float*  AXW0  = W + O_AXW0;
    float*  OUT0  = XCAT;          // aliases XCAT region, dead before XCAT written
    float*  CONVE = W + O_CONVE;   // ld 768, cols 766..767 zero
    float*  LWP   = W + O_LWP;     // written after AXW0 is dead, dead before P
    float*  QH    = W + O_QH;
    float*  KH    = W + O_KH;
    float*  P     = W + O_P;
    float*  ADJ2  = W + O_ADJ2;
    float*  XW1   = W + O_XW1;
    float*  OUTL1 = W + O_OUTL1;
    float*  H1    = W + O_H1;
    float*  XW0   = out;           // d_out as scratch; fully overwritten at the end

    const float divs = sqrtf(512.0f);

    // ---- GCN layer 0 ----
    rowsum_kernel<<<dim3(8192), dim3(256), 0, stream>>>(adj, DEN, 512);
    // AX = adj @ inputs (NN, batched)
    gemm_mfma_kernel<<<dim3(6, 4, 16), dim3(256), 0, stream>>>(
        adj, inp, AX, nullptr, 512, 768, 512, 512, 768, 768,
        262144LL, 393216LL, 393216LL, 1.f, 0, 1, 768);
    // XW0 = inputs @ W0^T (NT)
    gemm_mfma_kernel<<<dim3(6, 64, 1), dim3(256), 0, stream>>>(
        inp, W0w, XW0, nullptr, 8192, 768, 768, 768, 768, 768,
        0, 0, 0, 1.f, 0, 0, 768);
    // AXW0 = AX @ W0^T (NT)
    gemm_mfma_kernel<<<dim3(6, 64, 1), dim3(256), 0, stream>>>(
        AX, W0w, AXW0, nullptr, 8192, 768, 768, 768, 768, 768,
        0, 0, 0, 1.f, 0, 0, 768);
    gcn_epilogue_kernel<<<dim3(24576), dim3(256), 0, stream>>>(AXW0, XW0, W0b, DEN, OUT0);

    // ---- pad linearc_w (AFTER AXW0's last write — LWP lives where AXW0/P overlap) ----
    pad_lw_kernel<<<dim3(2304), dim3(256), 0, stream>>>(Lw, LWP);

    // ---- conv (mode 2) + linearc -> xcat ----
    gemm_mfma_kernel<<<dim3(6, 4, 16), dim3(256), 0, stream>>>(
        Cw, OUT0, CONVE, Cbi, 512, 768, 1536, 1536, 0, 768,
        0LL, 393216LL, 393216LL, 1.f, 1, 2, 766);
    gemm_mfma_kernel<<<dim3(6, 64, 1), dim3(256), 0, stream>>>(
        CONVE, LWP, XCAT + 768, Lb, 8192, 768, 768, 768, 768, 1536,
        0, 0, 0, 1.f, 0, 0, 768);
    copy_concat_kernel<<<dim3(24576), dim3(256), 0, stream>>>(inp, XCAT);

    // ---- attention per head: Q, K projections + scores ----
    for (int h = 0; h < 3; ++h) {
        gemm_mfma_kernel<<<dim3(4, 64, 1), dim3(256), 0, stream>>>(
            XCAT, Qw + (long long)h * 512 * 1536, QH, Qb + h * 512,
            8192, 512, 1536, 1536, 1536, 512, 0, 0, 0, 1.f, 0, 0, 512);
        gemm_mfma_kernel<<<dim3(4, 64, 1), dim3(256), 0, stream>>>(
            XCAT, Kw + (long long)h * 512 * 1536, KH, Kbi + h * 512,
            8192, 512, 1536, 1536, 1536, 512, 0, 0, 0, 1.f, 0, 0, 512);
        gemm_mfma_kernel<<<dim3(3, 4, 16), dim3(256), 0, stream>>>(
            QH, KH, P + (long long)h * 196608, nullptr,
            512, 384, 512, 512, 512, 384,
            262144LL, 262144LL, 589824LL, divs, 0, 0, 384);
    }

    // ---- softmax + decisions ----
    softmax_kernel<<<dim3(24576), dim3(128), 0, stream>>>(P);
    sums_kernel<<<dim3(48), dim3(256), 0, stream>>>(P, SUMS);
    decide_kernel<<<dim3(1), dim3(64), 0, stream>>>(SUMS, MIDX);
    top2_kernel<<<dim3(16), dim3(256), 0, stream>>>(P, MIDX, THR);
    adj2_kernel<<<dim3(16384), dim3(256), 0, stream>>>(P, MIDX, THR, ADJ2);
    extract_nnz_kernel<<<dim3(32), dim3(256), 0, stream>>>(ADJ2, NNZC, NNZJ, NNZV, DEN2);

    // ---- GCN layer 1 (sparse adj2) + fc ----
    gemm_mfma_kernel<<<dim3(6, 64, 1), dim3(256), 0, stream>>>(
        XCAT, W1w, XW1, nullptr, 8192, 768, 1536, 1536, 1536, 768,
        0, 0, 0, 1.f, 0, 0, 768);
    gcn1_epilogue_kernel<<<dim3(8192), dim3(256), 0, stream>>>(XW1, W1b, DEN2, NNZC, NNZJ, NNZV, OUTL1);
    gemm_mfma_kernel<<<dim3(6, 64, 1), dim3(256), 0, stream>>>(
        OUTL1, F1, H1, nullptr, 8192, 768, 768, 768, 768, 768,
        0, 0, 0, 1.f, 1, 0, 768);
    gemm_mfma_kernel<<<dim3(6, 64, 1), dim3(256), 0, stream>>>(
        H1, F2, out, nullptr, 8192, 768, 768, 768, 768, 768,
        0, 0, 0, 1.f, 0, 0, 768);
}

// Round 5
// 1931.121 us; speedup vs baseline: 3.1306x; 1.2459x over previous
//
#include <hip/hip_runtime.h>
#include <math.h>

// B=16, N=512, D=768, Dh=1536, HEADS=3, keys>=384 masked.
// All GEMMs: 128x128x32 MFMA tiles, bf16x2 split (3-pass), fp32 accumulate.
// Operands pre-converted to hi/lo bf16 "planes" (hi plane then lo plane, same
// byte footprint as f32). GEMM K-loop staging = pure 16B copies (no VALU cvt).
//
// Arena (float units), 30539776 floats (~122.2 MB):
//  S  [0, 131072): scalars/lists
//  X  [131072, 12713984): ph1 INPP planes[0,6.29M) -> OUT0 f32[0,6.29M)
//                         ph2+ XCAT planes (full 12.58M)
//                         after XW1 GEMM: F1P[0,0.59M) F2P[0.59,1.18M)
//  Z = 12713984, 17.83M:
//    ph1: AXp[0,6.29M) AXW0 f32[6.29,12.58M) W0P[12.58,13.17M)
//    ph2: CONVEp[0,6.29M) CwP[6.29,7.08M) LWPp[7.08,7.67M)
//    ph3: QHp[0,4.19M) KHp[4.19,8.39M) P f32[8.39,17.83M)
//    ph5: XW1 f32[4.19,10.49M) OUTL1p[10.49,16.78M) H1p[0,6.29M)
//  d_out: ph1 XW0 f32; ph2+ QwP[0,2.36M) KwP[2.36,4.72M) W1P[4.72,5.9M); final out.

namespace {

constexpr long long O_DEN  = 0;
constexpr long long O_DEN2 = 8192;
constexpr long long O_SUMP = 16384;   // 768 doubles = 1536 floats
constexpr long long O_THR  = 17920;
constexpr long long O_MIDX = 17936;
constexpr long long O_CNT  = 17952;
constexpr long long O_POS  = 17968;   // 16*16 ints
constexpr long long O_T2P  = 18224;   // 512 float2 = 1024 floats
constexpr long long O_NNZC = 19456;   // 8192 ints
constexpr long long O_NNZJ = 27648;   // 8192*4 ints
constexpr long long O_NNZV = 60416;   // 8192*4 floats -> ends 93184

constexpr long long O_X    = 131072;
constexpr long long OZ     = 131072 + 12582912;          // 12713984
constexpr long long TOTAL_FLOATS = OZ + 17825792;        // 30539776

typedef short bf16x8 __attribute__((ext_vector_type(8)));
typedef float f32x4 __attribute__((ext_vector_type(4)));
typedef unsigned short ushort_t;

__global__ void sentinel_kernel(float* out) {
    if (threadIdx.x == 0 && blockIdx.x == 0) out[0] = 1.0e6f;
}

// RNE f32 -> bf16 hi + bf16(residual)
__device__ __forceinline__ void cvt_split(float f, unsigned short& h, unsigned short& l) {
    union { float x; unsigned u; } a; a.x = f;
    unsigned hb = (a.u + 0x7FFFu + ((a.u >> 16) & 1u)) & 0xFFFF0000u;
    h = (unsigned short)(hb >> 16);
    union { unsigned u; float x; } b; b.u = hb;
    float r = f - b.x;
    union { float x; unsigned u; } c; c.x = r;
    l = (unsigned short)((c.u + 0x7FFFu + ((c.u >> 16) & 1u)) >> 16);
}

// ---------------- f32 -> planes converter (4 elems/thread) ----------------
__global__ void convert_planes_kernel(const float* __restrict__ src, unsigned short* __restrict__ dst,
                                      long long loOff, long long n4) {
    long long idx = (long long)blockIdx.x * 256 + threadIdx.x;
    if (idx >= n4) return;
    float4 v = ((const float4*)src)[idx];
    unsigned short h0,h1,h2,h3,l0,l1,l2,l3;
    cvt_split(v.x,h0,l0); cvt_split(v.y,h1,l1); cvt_split(v.z,h2,l2); cvt_split(v.w,h3,l3);
    uint2 hp, lp;
    hp.x = (unsigned)h0 | ((unsigned)h1 << 16); hp.y = (unsigned)h2 | ((unsigned)h3 << 16);
    lp.x = (unsigned)l0 | ((unsigned)l1 << 16); lp.y = (unsigned)l2 | ((unsigned)l3 << 16);
    *(uint2*)&dst[idx * 4] = hp;
    *(uint2*)&dst[loOff + idx * 4] = lp;
}

// ---------------- pad linearc_w [768,766] -> planes [768,768] ----------------
__global__ void pad_lw_kernel(const float* __restrict__ Lw, unsigned short* __restrict__ Lp) {
    int idx = blockIdx.x * 256 + threadIdx.x;  // 589824
    int n = idx / 768, k = idx - n * 768;
    float v = (k < 766) ? Lw[n * 766 + k] : 0.f;
    unsigned short h, l; cvt_split(v, h, l);
    Lp[idx] = h; Lp[589824 + idx] = l;
}

// ================= MFMA GEMM =================
// A[M,K] row-major. amode: 0=f32, 1=planes (lo at A+aLo elements).
// bmode: 1=NN f32 (B[k*ldb+n]), 2=conv f32 window (B[(k/3)*768+n+k%3], bias by m),
//        3=NT planes (B[n*ldb+k], lo at +bLo).
// cmode: 0=f32, 1=planes (lo at +cLo). n>=Nreal -> 0.
__global__ __launch_bounds__(256)
void gemm_mfma_kernel(const void* __restrict__ Av, const void* __restrict__ Bv,
                      void* __restrict__ Cv, const float* __restrict__ bias,
                      int M, int N, int K, int lda, int ldb, int ldc,
                      long long sA, long long sB, long long sC,
                      float divd, int relu,
                      int amode, long long aLo,
                      int bmode, long long bLo,
                      int cmode, long long cLo,
                      int Nreal)
{
    __shared__ __align__(16) unsigned short AhS[4][128][8];
    __shared__ __align__(16) unsigned short AlS[4][128][8];
    __shared__ __align__(16) unsigned short BhS[4][128][8];
    __shared__ __align__(16) unsigned short BlS[4][128][8];

    const int z = blockIdx.z;
    const int tid = threadIdx.x;
    const int m0 = blockIdx.y * 128, n0 = blockIdx.x * 128;
    const int lane = tid & 63, wave = tid >> 6;
    const int wm = (wave & 1) * 64, wn = (wave >> 1) * 64;
    const int lkh = lane >> 4, lm = lane & 15;

    const float* Af = (const float*)Av + z * sA;
    const unsigned short* Au = (const unsigned short*)Av + z * sA;
    const float* Bf = (const float*)Bv + z * sB;
    const unsigned short* Bu = (const unsigned short*)Bv + z * sB;
    float* Cf = (float*)Cv + z * sC;
    unsigned short* Cu = (unsigned short*)Cv + z * sC;

    f32x4 acc[4][4];
    #pragma unroll
    for (int i = 0; i < 4; ++i)
        #pragma unroll
        for (int j = 0; j < 4; ++j) acc[i][j] = (f32x4){0.f, 0.f, 0.f, 0.f};

    const int achunk = tid & 7, arow0 = tid >> 3;   // legacy f32 staging map
    const int bnc = tid & 31, bkr = tid >> 5;       // NN/conv staging map

    for (int k0 = 0; k0 < K; k0 += 32) {
        // ---- stage A ----
        if (amode == 1) {
            #pragma unroll
            for (int l = 0; l < 2; ++l) {
                const int c = tid + l * 256;
                const int row = c & 127, kc = c >> 7;
                const unsigned short* src = Au + (long long)(m0 + row) * lda + k0 + kc * 8;
                *(uint4*)&AhS[kc][row][0] = *(const uint4*)src;
                *(uint4*)&AlS[kc][row][0] = *(const uint4*)(src + aLo);
            }
        } else {
            const int kl = achunk * 4;
            const int kc = kl >> 3, kp = kl & 7;
            #pragma unroll
            for (int r = 0; r < 4; ++r) {
                const int row = arow0 + r * 32;
                const float4 v = *(const float4*)(Af + (long long)(m0 + row) * lda + (k0 + kl));
                unsigned short h0,h1,h2,h3,l0,l1,l2,l3;
                cvt_split(v.x,h0,l0); cvt_split(v.y,h1,l1);
                cvt_split(v.z,h2,l2); cvt_split(v.w,h3,l3);
                uint2 hp, lp;
                hp.x = (unsigned)h0 | ((unsigned)h1 << 16);
                hp.y = (unsigned)h2 | ((unsigned)h3 << 16);
                lp.x = (unsigned)l0 | ((unsigned)l1 << 16);
                lp.y = (unsigned)l2 | ((unsigned)l3 << 16);
                *(uint2*)&AhS[kc][row][kp] = hp;
                *(uint2*)&AlS[kc][row][kp] = lp;
            }
        }
        // ---- stage B ----
        if (bmode == 3) {
            #pragma unroll
            for (int l = 0; l < 2; ++l) {
                const int c = tid + l * 256;
                const int row = c & 127, kc = c >> 7;
                const unsigned short* src = Bu + (long long)(n0 + row) * ldb + k0 + kc * 8;
                *(uint4*)&BhS[kc][row][0] = *(const uint4*)src;
                *(uint4*)&BlS[kc][row][0] = *(const uint4*)(src + bLo);
            }
        } else {
            #pragma unroll
            for (int r = 0; r < 4; ++r) {
                const int k = bkr + r * 8;
                const int kg = k0 + k;
                float vv[4];
                if (bmode == 1) {
                    const float4 t = *(const float4*)(Bf + (long long)kg * ldb + (n0 + bnc * 4));
                    vv[0] = t.x; vv[1] = t.y; vv[2] = t.z; vv[3] = t.w;
                } else {
                    const int ii = kg / 3, k3 = kg - ii * 3;
                    const float* src = Bf + (long long)ii * 768 + (n0 + bnc * 4) + k3;
                    vv[0] = src[0]; vv[1] = src[1]; vv[2] = src[2]; vv[3] = src[3];
                }
                const int kc = k >> 3, kp = k & 7;
                #pragma unroll
                for (int q = 0; q < 4; ++q) {
                    unsigned short h, l;
                    cvt_split(vv[q], h, l);
                    BhS[kc][bnc * 4 + q][kp] = h;
                    BlS[kc][bnc * 4 + q][kp] = l;
                }
            }
        }
        __syncthreads();
        // ---- fragments + 3-pass MFMA ----
        bf16x8 ah[4], al[4], bh[4], bl[4];
        #pragma unroll
        for (int i = 0; i < 4; ++i) {
            ah[i] = *(const bf16x8*)&AhS[lkh][wm + i * 16 + lm][0];
            al[i] = *(const bf16x8*)&AlS[lkh][wm + i * 16 + lm][0];
        }
        #pragma unroll
        for (int j = 0; j < 4; ++j) {
            bh[j] = *(const bf16x8*)&BhS[lkh][wn + j * 16 + lm][0];
            bl[j] = *(const bf16x8*)&BlS[lkh][wn + j * 16 + lm][0];
        }
        #pragma unroll
        for (int i = 0; i < 4; ++i)
            #pragma unroll
            for (int j = 0; j < 4; ++j) {
                acc[i][j] = __builtin_amdgcn_mfma_f32_16x16x32_bf16(ah[i], bh[j], acc[i][j], 0, 0, 0);
                acc[i][j] = __builtin_amdgcn_mfma_f32_16x16x32_bf16(ah[i], bl[j], acc[i][j], 0, 0, 0);
                acc[i][j] = __builtin_amdgcn_mfma_f32_16x16x32_bf16(al[i], bh[j], acc[i][j], 0, 0, 0);
            }
        __syncthreads();
    }
    // ---- epilogue: C/D layout col=lane&15, row=(lane>>4)*4+reg ----
    const int erow = (lane >> 4) * 4;
    #pragma unroll
    for (int i = 0; i < 4; ++i) {
        #pragma unroll
        for (int reg = 0; reg < 4; ++reg) {
            const int m = m0 + wm + i * 16 + erow + reg;
            #pragma unroll
            for (int j = 0; j < 4; ++j) {
                const int n = n0 + wn + j * 16 + lm;
                float v = acc[i][j][reg];
                if (divd != 1.f) v = v / divd;
                if (bias) v += bias[bmode == 2 ? m : n];
                if (relu) v = fmaxf(v, 0.f);
                if (n >= Nreal) v = 0.f;
                if (cmode == 1) {
                    unsigned short h, l; cvt_split(v, h, l);
                    Cu[(long long)m * ldc + n] = h;
                    Cu[cLo + (long long)m * ldc + n] = l;
                } else {
                    Cf[(long long)m * ldc + n] = v;
                }
            }
        }
    }
}

// ---------------- row sum (+1) for adj ----------------
__global__ void rowsum_kernel(const float* __restrict__ A, float* __restrict__ out, int ncols) {
    const float* row = A + (long long)blockIdx.x * ncols;
    float s = 0.f;
    for (int j = threadIdx.x; j < ncols; j += 256) s += row[j];
    __shared__ float red[256];
    red[threadIdx.x] = s;
    __syncthreads();
    for (int st = 128; st > 0; st >>= 1) {
        if (threadIdx.x < st) red[threadIdx.x] += red[threadIdx.x + st];
        __syncthreads();
    }
    if (threadIdx.x == 0) out[blockIdx.x] = red[0] + 1.0f;
}

// ------------- GCN layer-0 epilogue (f32 in, f32 out) -------------
__global__ void gcn_epilogue_kernel(const float* __restrict__ axw, const float* __restrict__ xw,
                                    const float* __restrict__ bias, const float* __restrict__ denom,
                                    float* __restrict__ out)
{
    long long idx = (long long)blockIdx.x * 256 + threadIdx.x;  // 8192*768
    int m = (int)(idx / 768);
    int d = (int)(idx - (long long)m * 768);
    float bb = bias[d];
    float v = (axw[idx] + bb) / denom[m];
    out[idx] = fmaxf(v, 0.f) + xw[idx] + bb;
}

// ------------- inputs -> XCAT planes cols 0..767 -------------
__global__ void copy_concat_kernel(const float* __restrict__ inp, unsigned short* __restrict__ xcat)
{
    long long idx = (long long)blockIdx.x * 256 + threadIdx.x;  // 8192*768
    int m = (int)(idx / 768);
    int d = (int)(idx - (long long)m * 768);
    unsigned short h, l; cvt_split(inp[idx], h, l);
    xcat[(long long)m * 1536 + d] = h;
    xcat[12582912LL + (long long)m * 1536 + d] = l;
}

// ------------- row softmax over 384 stored cols (ld=384) -------------
__global__ void softmax_kernel(float* __restrict__ P)
{
    float* row = P + (long long)blockIdx.x * 384;
    const int t = threadIdx.x;  // 128 threads
    float v0 = row[t], v1 = row[t + 128], v2 = row[t + 256];
    float m = fmaxf(v0, fmaxf(v1, v2));
    #pragma unroll
    for (int off = 32; off > 0; off >>= 1) m = fmaxf(m, __shfl_down(m, off));
    __shared__ float redm[2];
    if ((t & 63) == 0) redm[t >> 6] = m;
    __syncthreads();
    m = fmaxf(redm[0], redm[1]);
    float e0 = expf(v0 - m), e1 = expf(v1 - m), e2 = expf(v2 - m);
    float s = e0 + e1 + e2;
    #pragma unroll
    for (int off = 32; off > 0; off >>= 1) s += __shfl_down(s, off);
    __shared__ float reds[2];
    if ((t & 63) == 0) reds[t >> 6] = s;
    __syncthreads();
    s = reds[0] + reds[1];
    row[t] = e0 / s;
    row[t + 128] = e1 / s;
    row[t + 256] = e2 / s;
}

// ------------- sums stage 1: 768 blocks, partial f64 sums -------------
__global__ void sums1_kernel(const float* __restrict__ P, double* __restrict__ sump)
{
    int blk = blockIdx.x;            // bh*16 + chunk
    int bh = blk >> 4, ch = blk & 15;
    const float* p = P + (long long)bh * 196608 + ch * 12288;
    double s = 0.0;
    for (int i = threadIdx.x; i < 12288; i += 256) s += (double)p[i];
    __shared__ double red[256];
    red[threadIdx.x] = s;
    __syncthreads();
    for (int st = 128; st > 0; st >>= 1) {
        if (threadIdx.x < st) red[threadIdx.x] += red[threadIdx.x + st];
        __syncthreads();
    }
    if (threadIdx.x == 0) sump[blk] = red[0];
}

// ------------- sums stage 2 + head decision -------------
__global__ void decide2_kernel(const double* __restrict__ sump, int* __restrict__ maxidx)
{
    __shared__ double s48[48];
    int t = threadIdx.x;  // 64
    if (t < 48) {
        double s = 0.0;
        for (int i = 0; i < 16; ++i) s += sump[t * 16 + i];
        s48[t] = s;
    }
    __syncthreads();
    if (t == 0) {
        float s[16][3], prob[16][3];
        for (int b = 0; b < 16; ++b)
            for (int h = 0; h < 3; ++h) s[b][h] = (float)s48[b * 3 + h];
        for (int h = 0; h < 3; ++h) {
            float m = -1e30f;
            for (int b = 0; b < 16; ++b) m = fmaxf(m, s[b][h]);
            float e[16]; float Z = 0.f;
            for (int b = 0; b < 16; ++b) { e[b] = expf(s[b][h] - m); Z += e[b]; }
            for (int b = 0; b < 16; ++b) prob[b][h] = e[b] / Z;
        }
        for (int b = 0; b < 16; ++b) {
            int best = 0; float bv = prob[b][0];
            for (int h = 1; h < 3; ++h) if (prob[b][h] > bv) { bv = prob[b][h]; best = h; }
            maxidx[b] = best;
        }
    }
}

// ------------- top2 stage 1: 512 blocks (b,chunk) -------------
__global__ void top2a_kernel(const float* __restrict__ P, const int* __restrict__ maxidx,
                             float2* __restrict__ t2p)
{
    int blk = blockIdx.x;
    int b = blk >> 5, ch = blk & 31;
    const float* p = P + ((long long)b * 3 + maxidx[b]) * 196608 + ch * 6144;
    float m1 = -1e30f, m2 = -1e30f;
    for (int i = threadIdx.x; i < 6144; i += 256) {
        float v = p[i];
        if (v > m1) { m2 = m1; m1 = v; }
        else if (v > m2) { m2 = v; }
    }
    __shared__ float r1[256], r2[256];
    r1[threadIdx.x] = m1; r2[threadIdx.x] = m2;
    __syncthreads();
    if (threadIdx.x == 0) {
        float M1 = -1e30f, M2 = -1e30f;
        for (int i = 0; i < 256; ++i) {
            float a = r1[i], c = r2[i];
            if (a > M1) { M2 = M1; M1 = a; } else if (a > M2) { M2 = a; }
            if (c > M1) { M2 = M1; M1 = c; } else if (c > M2) { M2 = c; }
        }
        t2p[blk] = make_float2(M1, M2);
    }
}

// ------------- top2 stage 2: thr[b] = 2nd largest -------------
__global__ void top2b_kernel(const float2* __restrict__ t2p, float* __restrict__ thr)
{
    int b = blockIdx.x;
    if (threadIdx.x != 0) return;
    float M1 = -1e30f, M2 = -1e30f;
    for (int i = 0; i < 32; ++i) {
        float2 v = t2p[b * 32 + i];
        if (v.x > M1) { M2 = M1; M1 = v.x; } else if (v.x > M2) { M2 = v.x; }
        if (v.y > M1) { M2 = M1; M1 = v.y; } else if (v.y > M2) { M2 = v.y; }
    }
    thr[b] = M2;
}

// ------------- init: CNT=0, NNZC=0, den2=1 -------------
__global__ void init_nnz_kernel(int* __restrict__ cntb, int* __restrict__ nnzc,
                                float* __restrict__ den2)
{
    int idx = blockIdx.x * 256 + threadIdx.x;
    if (idx < 16) cntb[idx] = 0;
    if (idx < 8192) { nnzc[idx] = 0; den2[idx] = 1.f; }
}

// ------------- scan P for p>=thr -> (i,j) positions (exact tie semantics) -------------
__global__ void scan_thr_kernel(const float* __restrict__ P, const int* __restrict__ maxidx,
                                const float* __restrict__ thr, int* __restrict__ cntb,
                                int* __restrict__ pos)
{
    int blk = blockIdx.x;            // 16*12
    int b = blk / 12, ch = blk % 12;
    const float* p = P + ((long long)b * 3 + maxidx[b]) * 196608;
    float t = thr[b];
    int base = ch * 16384;
    for (int l = 0; l < 64; ++l) {
        int idx = base + threadIdx.x + l * 256;
        if (p[idx] >= t) {
            int q = atomicAdd(&cntb[b], 1);
            if (q < 16) {
                int i = idx / 384, j = idx - i * 384;
                pos[b * 16 + q] = (i << 16) | j;
            }
        }
    }
}

// ------------- build nnz lists + den2 from positions -------------
__global__ void build_nnz_kernel(const int* __restrict__ cntb, const int* __restrict__ pos,
                                 int* __restrict__ nnzc, int* __restrict__ jn,
                                 float* __restrict__ jv, float* __restrict__ den2)
{
    int b = threadIdx.x;  // 64 threads, 16 active
    if (b >= 16 || blockIdx.x != 0) return;
    int c = cntb[b]; if (c > 16) c = 16;
    for (int e = 0; e < c; ++e) {
        int pk = pos[b * 16 + e];
        int i = pk >> 16, j = pk & 0xFFFF;
        float val;
        if (i == j) val = 1.f;
        else {
            int rev = (j << 16) | i;
            int found = 0;
            for (int e2 = 0; e2 < c; ++e2) if (pos[b * 16 + e2] == rev) found = 1;
            val = 1.f + (float)found;
        }
        int r = b * 512 + i;
        int slot = nnzc[r];
        if (slot < 4) { jn[r * 4 + slot] = b * 512 + j; jv[r * 4 + slot] = val; }
        nnzc[r] = slot + 1;
        den2[r] += val;
    }
}

// ------------- GCN layer-1 fused sparse epilogue -> OUTL1 planes -------------
__global__ void gcn1_epilogue_kernel(const float* __restrict__ XW1, const float* __restrict__ b1,
                                     const float* __restrict__ den2, const int* __restrict__ cnt,
                                     const int* __restrict__ jn, const float* __restrict__ jv,
                                     unsigned short* __restrict__ outp)
{
    int m = blockIdx.x;            // 8192 rows
    int c = cnt[m]; if (c > 4) c = 4;
    float d2 = den2[m];
    int js[4]; float vs[4];
    for (int s = 0; s < c; ++s) { js[s] = jn[m * 4 + s]; vs[s] = jv[m * 4 + s]; }
    const float* xrow = XW1 + (long long)m * 768;
    #pragma unroll
    for (int l = 0; l < 3; ++l) {
        int d = threadIdx.x + l * 256;
        float ax = 0.f;
        for (int s = 0; s < c; ++s) ax += vs[s] * XW1[(long long)js[s] * 768 + d];
        float bb = b1[d];
        float v = fmaxf((ax + bb) / d2, 0.f) + xrow[d] + bb;
        unsigned short h, lo; cvt_split(v, h, lo);
        outp[(long long)m * 768 + d] = h;
        outp[6291456LL + (long long)m * 768 + d] = lo;
    }
}

}  // namespace

extern "C" void kernel_launch(void* const* d_in, const int* in_sizes, int n_in,
                              void* d_out, int out_size, void* d_ws, size_t ws_size,
                              hipStream_t stream) {
    const float* adj = (const float*)d_in[0];
    const float* inp = (const float*)d_in[1];
    // d_in[2] = score_mask: fixed function of indices — never read.
    const float* W0w = (const float*)d_in[3];
    const float* W0b = (const float*)d_in[4];
    const float* W1w = (const float*)d_in[5];
    const float* W1b = (const float*)d_in[6];
    const float* Cw  = (const float*)d_in[7];
    const float* Cbi = (const float*)d_in[8];
    const float* Lw  = (const float*)d_in[9];
    const float* Lb  = (const float*)d_in[10];
    const float* F1  = (const float*)d_in[11];
    const float* F2  = (const float*)d_in[12];
    const float* Qw  = (const float*)d_in[13];
    const float* Qb  = (const float*)d_in[14];
    const float* Kw  = (const float*)d_in[15];
    const float* Kbi = (const float*)d_in[16];
    float* out = (float*)d_out;

    if (ws_size < (size_t)TOTAL_FLOATS * sizeof(float)) {
        sentinel_kernel<<<dim3(1), dim3(64), 0, stream>>>(out);
        return;
    }

    float* W = (float*)d_ws;
    float*   DEN   = W + O_DEN;
    float*   DEN2  = W + O_DEN2;
    double*  SUMP  = (double*)(W + O_SUMP);
    float*   THR   = W + O_THR;
    int*     MIDX  = (int*)(W + O_MIDX);
    int*     CNT   = (int*)(W + O_CNT);
    int*     POS   = (int*)(W + O_POS);
    float2*  T2P   = (float2*)(W + O_T2P);
    int*     NNZC  = (int*)(W + O_NNZC);
    int*     NNZJ  = (int*)(W + O_NNZJ);
    float*   NNZV  = W + O_NNZV;

    // X region
    unsigned short* INPP  = (unsigned short*)(W + O_X);
    float*          OUT0  = W + O_X;                       // f32, after INPP dead
    unsigned short* XCATp = (unsigned short*)(W + O_X);
    unsigned short* F1P   = (unsigned short*)(W + O_X);    // after XCAT dead
    unsigned short* F2P   = (unsigned short*)(W + O_X + 589824);
    // Z region
    unsigned short* AXp    = (unsigned short*)(W + OZ);
    float*          AXW0f  = W + OZ + 6291456;
    unsigned short* W0P    = (unsigned short*)(W + OZ + 12582912);
    unsigned short* CONVEp = (unsigned short*)(W + OZ);
    unsigned short* CwP    = (unsigned short*)(W + OZ + 6291456);
    unsigned short* LWPp   = (unsigned short*)(W + OZ + 7077888);
    unsigned short* QHp    = (unsigned short*)(W + OZ);
    unsigned short* KHp    = (unsigned short*)(W + OZ + 4194304);
    float*          P      = W + OZ + 8388608;
    float*          XW1f   = W + OZ + 4194304;
    unsigned short* OUTL1p = (unsigned short*)(W + OZ + 10485760);
    unsigned short* H1p    = (unsigned short*)(W + OZ);
    // d_out region
    float*          XW0f   = out;
    unsigned short* QwP    = (unsigned short*)out;
    unsigned short* KwP    = (unsigned short*)(out + 2359296);
    unsigned short* W1P    = (unsigned short*)(out + 4718592);

    const float divs = sqrtf(512.0f);
    const int BIGN = 1 << 30;

    // ---- phase 1: GCN layer 0 ----
    convert_planes_kernel<<<dim3(6144), dim3(256), 0, stream>>>(inp, INPP, 6291456, 1572864);
    convert_planes_kernel<<<dim3(576), dim3(256), 0, stream>>>(W0w, W0P, 589824, 147456);
    rowsum_kernel<<<dim3(8192), dim3(256), 0, stream>>>(adj, DEN, 512);
    // AX = adj @ inputs (A f32, B NN f32) -> planes
    gemm_mfma_kernel<<<dim3(6, 4, 16), dim3(256), 0, stream>>>(
        adj, inp, AXp, nullptr, 512, 768, 512, 512, 768, 768,
        262144LL, 393216LL, 393216LL, 1.f, 0, 0, 0, 1, 0, 1, 6291456LL, BIGN);
    // XW0 = inp @ W0^T -> f32 in d_out
    gemm_mfma_kernel<<<dim3(6, 64, 1), dim3(256), 0, stream>>>(
        INPP, W0P, XW0f, nullptr, 8192, 768, 768, 768, 768, 768,
        0, 0, 0, 1.f, 0, 1, 6291456LL, 3, 589824LL, 0, 0, BIGN);
    // AXW0 = AX @ W0^T -> f32
    gemm_mfma_kernel<<<dim3(6, 64, 1), dim3(256), 0, stream>>>(
        AXp, W0P, AXW0f, nullptr, 8192, 768, 768, 768, 768, 768,
        0, 0, 0, 1.f, 0, 1, 6291456LL, 3, 589824LL, 0, 0, BIGN);
    gcn_epilogue_kernel<<<dim3(24576), dim3(256), 0, stream>>>(AXW0f, XW0f, W0b, DEN, OUT0);

    // ---- weight conversions (d_out and Z+6.29M now free) ----
    convert_planes_kernel<<<dim3(768), dim3(256), 0, stream>>>(Cw, CwP, 786432, 196608);
    pad_lw_kernel<<<dim3(2304), dim3(256), 0, stream>>>(Lw, LWPp);
    convert_planes_kernel<<<dim3(2304), dim3(256), 0, stream>>>(Qw, QwP, 2359296, 589824);
    convert_planes_kernel<<<dim3(2304), dim3(256), 0, stream>>>(Kw, KwP, 2359296, 589824);
    convert_planes_kernel<<<dim3(1152), dim3(256), 0, stream>>>(W1w, W1P, 1179648, 294912);

    // ---- phase 2: conv + linearc -> xcat planes ----
    gemm_mfma_kernel<<<dim3(6, 4, 16), dim3(256), 0, stream>>>(
        CwP, OUT0, CONVEp, Cbi, 512, 768, 1536, 1536, 0, 768,
        0, 393216LL, 393216LL, 1.f, 1, 1, 786432LL, 2, 0, 1, 6291456LL, 766);
    gemm_mfma_kernel<<<dim3(6, 64, 1), dim3(256), 0, stream>>>(
        CONVEp, LWPp, (void*)(XCATp + 768), Lb, 8192, 768, 768, 768, 768, 1536,
        0, 0, 0, 1.f, 0, 1, 6291456LL, 3, 589824LL, 1, 12582912LL, BIGN);
    copy_concat_kernel<<<dim3(24576), dim3(256), 0, stream>>>(inp, XCATp);

    // ---- phase 3: attention per head ----
    for (int h = 0; h < 3; ++h) {
        gemm_mfma_kernel<<<dim3(4, 64, 1), dim3(256), 0, stream>>>(
            XCATp, QwP + (long long)h * 786432, QHp, Qb + h * 512,
            8192, 512, 1536, 1536, 1536, 512,
            0, 0, 0, 1.f, 0, 1, 12582912LL, 3, 2359296LL, 1, 4194304LL, BIGN);
        gemm_mfma_kernel<<<dim3(4, 64, 1), dim3(256), 0, stream>>>(
            XCATp, KwP + (long long)h * 786432, KHp, Kbi + h * 512,
            8192, 512, 1536, 1536, 1536, 512,
            0, 0, 0, 1.f, 0, 1, 12582912LL, 3, 2359296LL, 1, 4194304LL, BIGN);
        gemm_mfma_kernel<<<dim3(3, 4, 16), dim3(256), 0, stream>>>(
            QHp, KHp, P + (long long)h * 196608, nullptr,
            512, 384, 512, 512, 512, 384,
            262144LL, 262144LL, 589824LL, divs, 0, 1, 4194304LL, 3, 4194304LL, 0, 0, BIGN);
    }

    // ---- softmax + decisions ----
    softmax_kernel<<<dim3(24576), dim3(128), 0, stream>>>(P);
    sums1_kernel<<<dim3(768), dim3(256), 0, stream>>>(P, SUMP);
    decide2_kernel<<<dim3(1), dim3(64), 0, stream>>>(SUMP, MIDX);
    top2a_kernel<<<dim3(512), dim3(256), 0, stream>>>(P, MIDX, T2P);
    top2b_kernel<<<dim3(16), dim3(64), 0, stream>>>(T2P, THR);
    init_nnz_kernel<<<dim3(32), dim3(256), 0, stream>>>(CNT, NNZC, DEN2);
    scan_thr_kernel<<<dim3(192), dim3(256), 0, stream>>>(P, MIDX, THR, CNT, POS);
    build_nnz_kernel<<<dim3(1), dim3(64), 0, stream>>>(CNT, POS, NNZC, NNZJ, NNZV, DEN2);

    // ---- phase 5: GCN layer 1 (sparse adj2) + fc ----
    gemm_mfma_kernel<<<dim3(6, 64, 1), dim3(256), 0, stream>>>(
        XCATp, W1P, XW1f, nullptr, 8192, 768, 1536, 1536, 1536, 768,
        0, 0, 0, 1.f, 0, 1, 12582912LL, 3, 1179648LL, 0, 0, BIGN);
    convert_planes_kernel<<<dim3(576), dim3(256), 0, stream>>>(F1, F1P, 589824, 147456);
    convert_planes_kernel<<<dim3(576), dim3(256), 0, stream>>>(F2, F2P, 589824, 147456);
    gcn1_epilogue_kernel<<<dim3(8192), dim3(256), 0, stream>>>(XW1f, W1b, DEN2, NNZC, NNZJ, NNZV, OUTL1p);
    gemm_mfma_kernel<<<dim3(6, 64, 1), dim3(256), 0, stream>>>(
        OUTL1p, F1P, H1p, nullptr, 8192, 768, 768, 768, 768, 768,
        0, 0, 0, 1.f, 1, 1, 6291456LL, 3, 589824LL, 1, 6291456LL, BIGN);
    gemm_mfma_kernel<<<dim3(6, 64, 1), dim3(256), 0, stream>>>(
        H1p, F2P, out, nullptr, 8192, 768, 768, 768, 768, 768,
        0, 0, 0, 1.f, 0, 1, 6291456LL, 3, 589824LL, 0, 0, BIGN);
}

// Round 6
// 1726.821 us; speedup vs baseline: 3.5010x; 1.1183x over previous
//
#include <hip/hip_runtime.h>
#include <math.h>

// B=16, N=512, D=768, Dh=1536, HEADS=3, keys>=384 masked.
// GEMMs: 128x64 MFMA tiles (16x16x32), bf16x2 split (3-pass), fp32 accumulate.
// Operands pre-split into hi/lo bf16 planes; staging via global_load_lds (16B).
//
// Arena (float units), 30539776 (~122.2 MB):
//  S [0,131072): scalars/lists (+QKB bias at 93184)
//  X [131072,+12582912): INPP planes -> OUT0 f32 -> XCATp planes -> F1P/F2P
//  Z = 12713984 (+17825792):
//   ph1: AXp[0,6.29M) AXW0f[6.29,12.58M) W0P[12.58,13.17M)
//   ph2: CONVEp[0,6.29M) CwP[6.29,7.08M) LWPp[7.08,7.67M)
//   ph3: QKp planes[0,8.39M) P f32[8.39,17.83M)
//   ph5: XW1f[0,6.29M) OUTL1p[6.29,12.58M) H1p[0,6.29M after XW1f dead)
//  d_out: ph1 XW0f f32; then QKwP[0,4.72M) W1P[4.72,5.9M); final out.

namespace {

constexpr long long O_DEN  = 0;
constexpr long long O_DEN2 = 8192;
constexpr long long O_SUMP = 16384;
constexpr long long O_THR  = 17920;
constexpr long long O_MIDX = 17936;
constexpr long long O_CNT  = 17952;
constexpr long long O_POS  = 17968;
constexpr long long O_T2P  = 18224;
constexpr long long O_NNZC = 19456;
constexpr long long O_NNZJ = 27648;
constexpr long long O_NNZV = 60416;
constexpr long long O_QKB  = 93184;   // 3072 floats

constexpr long long O_X    = 131072;
constexpr long long OZ     = 131072 + 12582912;          // 12713984
constexpr long long TOTAL_FLOATS = OZ + 17825792;        // 30539776

typedef short bf16x8 __attribute__((ext_vector_type(8)));
typedef float f32x4 __attribute__((ext_vector_type(4)));

__global__ void sentinel_kernel(float* out) {
    if (threadIdx.x == 0 && blockIdx.x == 0) out[0] = 1.0e6f;
}

// RNE f32 -> bf16 hi + bf16(residual)
__device__ __forceinline__ void cvt_split(float f, unsigned short& h, unsigned short& l) {
    union { float x; unsigned u; } a; a.x = f;
    unsigned hb = (a.u + 0x7FFFu + ((a.u >> 16) & 1u)) & 0xFFFF0000u;
    h = (unsigned short)(hb >> 16);
    union { unsigned u; float x; } b; b.u = hb;
    float r = f - b.x;
    union { float x; unsigned u; } c; c.x = r;
    l = (unsigned short)((c.u + 0x7FFFu + ((c.u >> 16) & 1u)) >> 16);
}

// async 16B global->LDS (lds dest: wave-uniform base + lane*16)
__device__ __forceinline__ void gl_lds16(const unsigned short* g, unsigned short* l) {
    __builtin_amdgcn_global_load_lds(
        (const __attribute__((address_space(1))) unsigned int*)g,
        (__attribute__((address_space(3))) unsigned int*)l,
        16, 0, 0);
}

// ---------------- f32 -> planes converter ----------------
__global__ void convert_planes_kernel(const float* __restrict__ src, unsigned short* __restrict__ dst,
                                      long long loOff, long long n4) {
    long long idx = (long long)blockIdx.x * 256 + threadIdx.x;
    if (idx >= n4) return;
    float4 v = ((const float4*)src)[idx];
    unsigned short h0,h1,h2,h3,l0,l1,l2,l3;
    cvt_split(v.x,h0,l0); cvt_split(v.y,h1,l1); cvt_split(v.z,h2,l2); cvt_split(v.w,h3,l3);
    uint2 hp, lp;
    hp.x = (unsigned)h0 | ((unsigned)h1 << 16); hp.y = (unsigned)h2 | ((unsigned)h3 << 16);
    lp.x = (unsigned)l0 | ((unsigned)l1 << 16); lp.y = (unsigned)l2 | ((unsigned)l3 << 16);
    *(uint2*)&dst[idx * 4] = hp;
    *(uint2*)&dst[loOff + idx * 4] = lp;
}

// ---------------- pad linearc_w [768,766] -> planes [768,768] ----------------
__global__ void pad_lw_kernel(const float* __restrict__ Lw, unsigned short* __restrict__ Lp) {
    int idx = blockIdx.x * 256 + threadIdx.x;  // 589824
    int n = idx / 768, k = idx - n * 768;
    float v = (k < 766) ? Lw[n * 766 + k] : 0.f;
    unsigned short h, l; cvt_split(v, h, l);
    Lp[idx] = h; Lp[589824 + idx] = l;
}

// ---------------- stacked QK weights -> planes [3][1024][1536] ----------------
__global__ void convert_qkw_kernel(const float* __restrict__ Qw, const float* __restrict__ Kw,
                                   unsigned short* __restrict__ dst) {
    long long idx = (long long)blockIdx.x * 256 + threadIdx.x;  // < 1179648
    if (idx >= 1179648) return;
    long long e = idx * 4;
    int h = (int)(e / 1572864);
    int rem = (int)(e - (long long)h * 1572864);
    int row = rem / 1536, k = rem - row * 1536;
    const float* src = (row < 512) ? (Qw + ((long long)(h * 512 + row) * 1536 + k))
                                   : (Kw + ((long long)(h * 512 + row - 512) * 1536 + k));
    float4 v = *(const float4*)src;
    unsigned short h0,h1,h2,h3,l0,l1,l2,l3;
    cvt_split(v.x,h0,l0); cvt_split(v.y,h1,l1); cvt_split(v.z,h2,l2); cvt_split(v.w,h3,l3);
    uint2 hp, lp;
    hp.x = (unsigned)h0 | ((unsigned)h1 << 16); hp.y = (unsigned)h2 | ((unsigned)h3 << 16);
    lp.x = (unsigned)l0 | ((unsigned)l1 << 16); lp.y = (unsigned)l2 | ((unsigned)l3 << 16);
    *(uint2*)&dst[e] = hp;
    *(uint2*)&dst[4718592 + e] = lp;
}

// ---------------- stacked QK bias [3][1024] ----------------
__global__ void qkb_kernel(const float* __restrict__ Qb, const float* __restrict__ Kb,
                           float* __restrict__ qkb) {
    int i = blockIdx.x * 256 + threadIdx.x;
    if (i >= 3072) return;
    int h = i >> 10, r = i & 1023;
    qkb[i] = (r < 512) ? Qb[h * 512 + r] : Kb[h * 512 + r - 512];
}

// ================= MFMA GEMM, 128(M) x 64(N) tile =================
// amode: 0=f32 (VALU split), 1=planes (lo at +aLo elems, async staging)
// bmode: 1=NN f32, 2=conv f32 window (bias by m), 3=NT planes (lo at +bLo, async)
// cmode: 0=f32, 1=planes (lo at +cLo). n>=Nreal -> 0.
__global__ __launch_bounds__(256, 4)
void gemm_mfma_kernel(const void* __restrict__ Av, const void* __restrict__ Bv,
                      void* __restrict__ Cv, const float* __restrict__ bias,
                      int M, int N, int K, int lda, int ldb, int ldc,
                      long long sA, long long sB, long long sC,
                      float divd, int relu,
                      int amode, long long aLo,
                      int bmode, long long bLo,
                      int cmode, long long cLo,
                      int Nreal)
{
    __shared__ __align__(16) unsigned short AhS[4][128][8];
    __shared__ __align__(16) unsigned short AlS[4][128][8];
    __shared__ __align__(16) unsigned short BhS[4][64][8];
    __shared__ __align__(16) unsigned short BlS[4][64][8];

    const int z = blockIdx.z;
    const int tid = threadIdx.x;
    const int m0 = blockIdx.y * 128, n0 = blockIdx.x * 64;
    const int lane = tid & 63, wave = tid >> 6;
    const int wm = (wave & 1) * 64, wn = (wave >> 1) * 32;
    const int lkh = lane >> 4, lm = lane & 15;

    const float* Af = (const float*)Av + z * sA;
    const unsigned short* Au = (const unsigned short*)Av + z * sA;
    const float* Bf = (const float*)Bv + z * sB;
    const unsigned short* Bu = (const unsigned short*)Bv + z * sB;
    float* Cf = (float*)Cv + z * sC;
    unsigned short* Cu = (unsigned short*)Cv + z * sC;

    f32x4 acc[4][2];
    #pragma unroll
    for (int i = 0; i < 4; ++i)
        #pragma unroll
        for (int j = 0; j < 2; ++j) acc[i][j] = (f32x4){0.f, 0.f, 0.f, 0.f};

    const int achunk = tid & 7, arow0 = tid >> 3;   // f32-A staging map
    const int bnc = tid & 15, bkr = tid >> 4;       // NN/conv B staging map

    for (int k0 = 0; k0 < K; k0 += 32) {
        // ---- stage A (128 x 32) ----
        if (amode == 1) {
            #pragma unroll
            for (int l = 0; l < 2; ++l) {
                const int q = l * 4 + wave;               // 0..7
                const int row = ((q & 1) << 6) + lane;    // row within tile
                const unsigned short* g = Au + (long long)(m0 + row) * lda + k0 + ((q >> 1) << 3);
                gl_lds16(g, &AhS[q >> 1][(q & 1) << 6][0]);
                gl_lds16(g + aLo, &AlS[q >> 1][(q & 1) << 6][0]);
            }
        } else {
            const int kl = achunk * 4;
            const int kc = kl >> 3, kp = kl & 7;
            #pragma unroll
            for (int r = 0; r < 4; ++r) {
                const int row = arow0 + r * 32;
                const float4 v = *(const float4*)(Af + (long long)(m0 + row) * lda + (k0 + kl));
                unsigned short h0,h1,h2,h3,l0,l1,l2,l3;
                cvt_split(v.x,h0,l0); cvt_split(v.y,h1,l1);
                cvt_split(v.z,h2,l2); cvt_split(v.w,h3,l3);
                uint2 hp, lp;
                hp.x = (unsigned)h0 | ((unsigned)h1 << 16);
                hp.y = (unsigned)h2 | ((unsigned)h3 << 16);
                lp.x = (unsigned)l0 | ((unsigned)l1 << 16);
                lp.y = (unsigned)l2 | ((unsigned)l3 << 16);
                *(uint2*)&AhS[kc][row][kp] = hp;
                *(uint2*)&AlS[kc][row][kp] = lp;
            }
        }
        // ---- stage B (64 x 32) ----
        if (bmode == 3) {
            const unsigned short* g = Bu + (long long)(n0 + lane) * ldb + k0 + (wave << 3);
            gl_lds16(g, &BhS[wave][0][0]);
            gl_lds16(g + bLo, &BlS[wave][0][0]);
        } else {
            #pragma unroll
            for (int r = 0; r < 2; ++r) {
                const int k = bkr + r * 16;
                const int kg = k0 + k;
                float vv[4];
                if (bmode == 1) {
                    const float4 t = *(const float4*)(Bf + (long long)kg * ldb + (n0 + bnc * 4));
                    vv[0] = t.x; vv[1] = t.y; vv[2] = t.z; vv[3] = t.w;
                } else {
                    const int ii = kg / 3, k3 = kg - ii * 3;
                    const float* src = Bf + (long long)ii * 768 + (n0 + bnc * 4) + k3;
                    vv[0] = src[0]; vv[1] = src[1]; vv[2] = src[2]; vv[3] = src[3];
                }
                const int kc = k >> 3, kp = k & 7;
                #pragma unroll
                for (int q = 0; q < 4; ++q) {
                    unsigned short h, l;
                    cvt_split(vv[q], h, l);
                    BhS[kc][bnc * 4 + q][kp] = h;
                    BlS[kc][bnc * 4 + q][kp] = l;
                }
            }
        }
        __syncthreads();
        // ---- fragments + 3-pass MFMA ----
        bf16x8 ah[4], al[4], bh[2], bl[2];
        #pragma unroll
        for (int i = 0; i < 4; ++i) {
            ah[i] = *(const bf16x8*)&AhS[lkh][wm + i * 16 + lm][0];
            al[i] = *(const bf16x8*)&AlS[lkh][wm + i * 16 + lm][0];
        }
        #pragma unroll
        for (int j = 0; j < 2; ++j) {
            bh[j] = *(const bf16x8*)&BhS[lkh][wn + j * 16 + lm][0];
            bl[j] = *(const bf16x8*)&BlS[lkh][wn + j * 16 + lm][0];
        }
        #pragma unroll
        for (int i = 0; i < 4; ++i)
            #pragma unroll
            for (int j = 0; j < 2; ++j) {
                acc[i][j] = __builtin_amdgcn_mfma_f32_16x16x32_bf16(ah[i], bh[j], acc[i][j], 0, 0, 0);
                acc[i][j] = __builtin_amdgcn_mfma_f32_16x16x32_bf16(ah[i], bl[j], acc[i][j], 0, 0, 0);
                acc[i][j] = __builtin_amdgcn_mfma_f32_16x16x32_bf16(al[i], bh[j], acc[i][j], 0, 0, 0);
            }
        __syncthreads();
    }
    // ---- epilogue: C/D layout col=lane&15, row=(lane>>4)*4+reg ----
    const int erow = (lane >> 4) * 4;
    #pragma unroll
    for (int i = 0; i < 4; ++i) {
        #pragma unroll
        for (int reg = 0; reg < 4; ++reg) {
            const int m = m0 + wm + i * 16 + erow + reg;
            #pragma unroll
            for (int j = 0; j < 2; ++j) {
                const int n = n0 + wn + j * 16 + lm;
                float v = acc[i][j][reg];
                if (divd != 1.f) v = v / divd;
                if (bias) v += bias[bmode == 2 ? m : n];
                if (relu) v = fmaxf(v, 0.f);
                if (n >= Nreal) v = 0.f;
                if (cmode == 1) {
                    unsigned short h, l; cvt_split(v, h, l);
                    Cu[(long long)m * ldc + n] = h;
                    Cu[cLo + (long long)m * ldc + n] = l;
                } else {
                    Cf[(long long)m * ldc + n] = v;
                }
            }
        }
    }
}

// ---------------- row sum (+1) for adj ----------------
__global__ void rowsum_kernel(const float* __restrict__ A, float* __restrict__ out, int ncols) {
    const float* row = A + (long long)blockIdx.x * ncols;
    float s = 0.f;
    for (int j = threadIdx.x; j < ncols; j += 256) s += row[j];
    __shared__ float red[256];
    red[threadIdx.x] = s;
    __syncthreads();
    for (int st = 128; st > 0; st >>= 1) {
        if (threadIdx.x < st) red[threadIdx.x] += red[threadIdx.x + st];
        __syncthreads();
    }
    if (threadIdx.x == 0) out[blockIdx.x] = red[0] + 1.0f;
}

// ------------- GCN layer-0 epilogue -------------
__global__ void gcn_epilogue_kernel(const float* __restrict__ axw, const float* __restrict__ xw,
                                    const float* __restrict__ bias, const float* __restrict__ denom,
                                    float* __restrict__ out)
{
    long long idx = (long long)blockIdx.x * 256 + threadIdx.x;  // 8192*768
    int m = (int)(idx / 768);
    int d = (int)(idx - (long long)m * 768);
    float bb = bias[d];
    float v = (axw[idx] + bb) / denom[m];
    out[idx] = fmaxf(v, 0.f) + xw[idx] + bb;
}

// ------------- inputs -> XCAT planes cols 0..767 -------------
__global__ void copy_concat_kernel(const float* __restrict__ inp, unsigned short* __restrict__ xcat)
{
    long long idx = (long long)blockIdx.x * 256 + threadIdx.x;  // 8192*768
    int m = (int)(idx / 768);
    int d = (int)(idx - (long long)m * 768);
    unsigned short h, l; cvt_split(inp[idx], h, l);
    xcat[(long long)m * 1536 + d] = h;
    xcat[12582912LL + (long long)m * 1536 + d] = l;
}

// ------------- row softmax over 384 stored cols (ld=384) -------------
__global__ void softmax_kernel(float* __restrict__ P)
{
    float* row = P + (long long)blockIdx.x * 384;
    const int t = threadIdx.x;  // 128
    float v0 = row[t], v1 = row[t + 128], v2 = row[t + 256];
    float m = fmaxf(v0, fmaxf(v1, v2));
    #pragma unroll
    for (int off = 32; off > 0; off >>= 1) m = fmaxf(m, __shfl_down(m, off));
    __shared__ float redm[2];
    if ((t & 63) == 0) redm[t >> 6] = m;
    __syncthreads();
    m = fmaxf(redm[0], redm[1]);
    float e0 = expf(v0 - m), e1 = expf(v1 - m), e2 = expf(v2 - m);
    float s = e0 + e1 + e2;
    #pragma unroll
    for (int off = 32; off > 0; off >>= 1) s += __shfl_down(s, off);
    __shared__ float reds[2];
    if ((t & 63) == 0) reds[t >> 6] = s;
    __syncthreads();
    s = reds[0] + reds[1];
    row[t] = e0 / s;
    row[t + 128] = e1 / s;
    row[t + 256] = e2 / s;
}

// ------------- sums stage 1 (f64 partials) -------------
__global__ void sums1_kernel(const float* __restrict__ P, double* __restrict__ sump)
{
    int blk = blockIdx.x;
    int bh = blk >> 4, ch = blk & 15;
    const float* p = P + (long long)bh * 196608 + ch * 12288;
    double s = 0.0;
    for (int i = threadIdx.x; i < 12288; i += 256) s += (double)p[i];
    __shared__ double red[256];
    red[threadIdx.x] = s;
    __syncthreads();
    for (int st = 128; st > 0; st >>= 1) {
        if (threadIdx.x < st) red[threadIdx.x] += red[threadIdx.x + st];
        __syncthreads();
    }
    if (threadIdx.x == 0) sump[blk] = red[0];
}

// ------------- sums stage 2 + head decision -------------
__global__ void decide2_kernel(const double* __restrict__ sump, int* __restrict__ maxidx)
{
    __shared__ double s48[48];
    int t = threadIdx.x;
    if (t < 48) {
        double s = 0.0;
        for (int i = 0; i < 16; ++i) s += sump[t * 16 + i];
        s48[t] = s;
    }
    __syncthreads();
    if (t == 0) {
        float s[16][3], prob[16][3];
        for (int b = 0; b < 16; ++b)
            for (int h = 0; h < 3; ++h) s[b][h] = (float)s48[b * 3 + h];
        for (int h = 0; h < 3; ++h) {
            float m = -1e30f;
            for (int b = 0; b < 16; ++b) m = fmaxf(m, s[b][h]);
            float e[16]; float Z = 0.f;
            for (int b = 0; b < 16; ++b) { e[b] = expf(s[b][h] - m); Z += e[b]; }
            for (int b = 0; b < 16; ++b) prob[b][h] = e[b] / Z;
        }
        for (int b = 0; b < 16; ++b) {
            int best = 0; float bv = prob[b][0];
            for (int h = 1; h < 3; ++h) if (prob[b][h] > bv) { bv = prob[b][h]; best = h; }
            maxidx[b] = best;
        }
    }
}

// ------------- top2 stage 1 -------------
__global__ void top2a_kernel(const float* __restrict__ P, const int* __restrict__ maxidx,
                             float2* __restrict__ t2p)
{
    int blk = blockIdx.x;
    int b = blk >> 5, ch = blk & 31;
    const float* p = P + ((long long)b * 3 + maxidx[b]) * 196608 + ch * 6144;
    float m1 = -1e30f, m2 = -1e30f;
    for (int i = threadIdx.x; i < 6144; i += 256) {
        float v = p[i];
        if (v > m1) { m2 = m1; m1 = v; }
        else if (v > m2) { m2 = v; }
    }
    __shared__ float r1[256], r2[256];
    r1[threadIdx.x] = m1; r2[threadIdx.x] = m2;
    __syncthreads();
    if (threadIdx.x == 0) {
        float M1 = -1e30f, M2 = -1e30f;
        for (int i = 0; i < 256; ++i) {
            float a = r1[i], c = r2[i];
            if (a > M1) { M2 = M1; M1 = a; } else if (a > M2) { M2 = a; }
            if (c > M1) { M2 = M1; M1 = c; } else if (c > M2) { M2 = c; }
        }
        t2p[blk] = make_float2(M1, M2);
    }
}

// ------------- top2 stage 2 -------------
__global__ void top2b_kernel(const float2* __restrict__ t2p, float* __restrict__ thr)
{
    int b = blockIdx.x;
    if (threadIdx.x != 0) return;
    float M1 = -1e30f, M2 = -1e30f;
    for (int i = 0; i < 32; ++i) {
        float2 v = t2p[b * 32 + i];
        if (v.x > M1) { M2 = M1; M1 = v.x; } else if (v.x > M2) { M2 = v.x; }
        if (v.y > M1) { M2 = M1; M1 = v.y; } else if (v.y > M2) { M2 = v.y; }
    }
    thr[b] = M2;
}

// ------------- init nnz state -------------
__global__ void init_nnz_kernel(int* __restrict__ cntb, int* __restrict__ nnzc,
                                float* __restrict__ den2)
{
    int idx = blockIdx.x * 256 + threadIdx.x;
    if (idx < 16) cntb[idx] = 0;
    if (idx < 8192) { nnzc[idx] = 0; den2[idx] = 1.f; }
}

// ------------- scan P for p>=thr (exact >= tie semantics) -------------
__global__ void scan_thr_kernel(const float* __restrict__ P, const int* __restrict__ maxidx,
                                const float* __restrict__ thr, int* __restrict__ cntb,
                                int* __restrict__ pos)
{
    int blk = blockIdx.x;            // 16*12
    int b = blk / 12, ch = blk % 12;
    const float* p = P + ((long long)b * 3 + maxidx[b]) * 196608;
    float t = thr[b];
    int base = ch * 16384;
    for (int l = 0; l < 64; ++l) {
        int idx = base + threadIdx.x + l * 256;
        if (p[idx] >= t) {
            int q = atomicAdd(&cntb[b], 1);
            if (q < 16) {
                int i = idx / 384, j = idx - i * 384;
                pos[b * 16 + q] = (i << 16) | j;
            }
        }
    }
}

// ------------- build nnz lists + den2 -------------
__global__ void build_nnz_kernel(const int* __restrict__ cntb, const int* __restrict__ pos,
                                 int* __restrict__ nnzc, int* __restrict__ jn,
                                 float* __restrict__ jv, float* __restrict__ den2)
{
    int b = threadIdx.x;
    if (b >= 16 || blockIdx.x != 0) return;
    int c = cntb[b]; if (c > 16) c = 16;
    for (int e = 0; e < c; ++e) {
        int pk = pos[b * 16 + e];
        int i = pk >> 16, j = pk & 0xFFFF;
        float val;
        if (i == j) val = 1.f;
        else {
            int rev = (j << 16) | i;
            int found = 0;
            for (int e2 = 0; e2 < c; ++e2) if (pos[b * 16 + e2] == rev) found = 1;
            val = 1.f + (float)found;
        }
        int r = b * 512 + i;
        int slot = nnzc[r];
        if (slot < 4) { jn[r * 4 + slot] = b * 512 + j; jv[r * 4 + slot] = val; }
        nnzc[r] = slot + 1;
        den2[r] += val;
    }
}

// ------------- GCN layer-1 fused sparse epilogue -> OUTL1 planes -------------
__global__ void gcn1_epilogue_kernel(const float* __restrict__ XW1, const float* __restrict__ b1,
                                     const float* __restrict__ den2, const int* __restrict__ cnt,
                                     const int* __restrict__ jn, const float* __restrict__ jv,
                                     unsigned short* __restrict__ outp)
{
    int m = blockIdx.x;
    int c = cnt[m]; if (c > 4) c = 4;
    float d2 = den2[m];
    int js[4]; float vs[4];
    for (int s = 0; s < c; ++s) { js[s] = jn[m * 4 + s]; vs[s] = jv[m * 4 + s]; }
    const float* xrow = XW1 + (long long)m * 768;
    #pragma unroll
    for (int l = 0; l < 3; ++l) {
        int d = threadIdx.x + l * 256;
        float ax = 0.f;
        for (int s = 0; s < c; ++s) ax += vs[s] * XW1[(long long)js[s] * 768 + d];
        float bb = b1[d];
        float v = fmaxf((ax + bb) / d2, 0.f) + xrow[d] + bb;
        unsigned short h, lo; cvt_split(v, h, lo);
        outp[(long long)m * 768 + d] = h;
        outp[6291456LL + (long long)m * 768 + d] = lo;
    }
}

}  // namespace

extern "C" void kernel_launch(void* const* d_in, const int* in_sizes, int n_in,
                              void* d_out, int out_size, void* d_ws, size_t ws_size,
                              hipStream_t stream) {
    const float* adj = (const float*)d_in[0];
    const float* inp = (const float*)d_in[1];
    const float* W0w = (const float*)d_in[3];
    const float* W0b = (const float*)d_in[4];
    const float* W1w = (const float*)d_in[5];
    const float* W1b = (const float*)d_in[6];
    const float* Cw  = (const float*)d_in[7];
    const float* Cbi = (const float*)d_in[8];
    const float* Lw  = (const float*)d_in[9];
    const float* Lb  = (const float*)d_in[10];
    const float* F1  = (const float*)d_in[11];
    const float* F2  = (const float*)d_in[12];
    const float* Qw  = (const float*)d_in[13];
    const float* Qb  = (const float*)d_in[14];
    const float* Kw  = (const float*)d_in[15];
    const float* Kbi = (const float*)d_in[16];
    float* out = (float*)d_out;

    if (ws_size < (size_t)TOTAL_FLOATS * sizeof(float)) {
        sentinel_kernel<<<dim3(1), dim3(64), 0, stream>>>(out);
        return;
    }

    float* W = (float*)d_ws;
    float*   DEN   = W + O_DEN;
    float*   DEN2  = W + O_DEN2;
    double*  SUMP  = (double*)(W + O_SUMP);
    float*   THR   = W + O_THR;
    int*     MIDX  = (int*)(W + O_MIDX);
    int*     CNT   = (int*)(W + O_CNT);
    int*     POS   = (int*)(W + O_POS);
    float2*  T2P   = (float2*)(W + O_T2P);
    int*     NNZC  = (int*)(W + O_NNZC);
    int*     NNZJ  = (int*)(W + O_NNZJ);
    float*   NNZV  = W + O_NNZV;
    float*   QKB   = W + O_QKB;

    unsigned short* INPP  = (unsigned short*)(W + O_X);
    float*          OUT0  = W + O_X;
    unsigned short* XCATp = (unsigned short*)(W + O_X);
    unsigned short* F1P   = (unsigned short*)(W + O_X);
    unsigned short* F2P   = (unsigned short*)(W + O_X + 589824);

    unsigned short* AXp    = (unsigned short*)(W + OZ);
    float*          AXW0f  = W + OZ + 6291456;
    unsigned short* W0P    = (unsigned short*)(W + OZ + 12582912);
    unsigned short* CONVEp = (unsigned short*)(W + OZ);
    unsigned short* CwP    = (unsigned short*)(W + OZ + 6291456);
    unsigned short* LWPp   = (unsigned short*)(W + OZ + 7077888);
    unsigned short* QKp    = (unsigned short*)(W + OZ);
    float*          P      = W + OZ + 8388608;
    float*          XW1f   = W + OZ;
    unsigned short* OUTL1p = (unsigned short*)(W + OZ + 6291456);
    unsigned short* H1p    = (unsigned short*)(W + OZ);

    float*          XW0f   = out;
    unsigned short* QKwP   = (unsigned short*)out;
    unsigned short* W1P    = (unsigned short*)(out + 4718592);

    const float divs = sqrtf(512.0f);
    const int BIGN = 1 << 30;

    // ---- phase 1: GCN layer 0 ----
    convert_planes_kernel<<<dim3(6144), dim3(256), 0, stream>>>(inp, INPP, 6291456, 1572864);
    convert_planes_kernel<<<dim3(576), dim3(256), 0, stream>>>(W0w, W0P, 589824, 147456);
    qkb_kernel<<<dim3(12), dim3(256), 0, stream>>>(Qb, Kbi, QKB);
    rowsum_kernel<<<dim3(8192), dim3(256), 0, stream>>>(adj, DEN, 512);
    // AX = adj @ inputs -> planes
    gemm_mfma_kernel<<<dim3(12, 4, 16), dim3(256), 0, stream>>>(
        adj, inp, AXp, nullptr, 512, 768, 512, 512, 768, 768,
        262144LL, 393216LL, 393216LL, 1.f, 0, 0, 0, 1, 0, 1, 6291456LL, BIGN);
    // XW0 = inp @ W0^T -> f32 (d_out)
    gemm_mfma_kernel<<<dim3(12, 64, 1), dim3(256), 0, stream>>>(
        INPP, W0P, XW0f, nullptr, 8192, 768, 768, 768, 768, 768,
        0, 0, 0, 1.f, 0, 1, 6291456LL, 3, 589824LL, 0, 0, BIGN);
    // AXW0 = AX @ W0^T -> f32
    gemm_mfma_kernel<<<dim3(12, 64, 1), dim3(256), 0, stream>>>(
        AXp, W0P, AXW0f, nullptr, 8192, 768, 768, 768, 768, 768,
        0, 0, 0, 1.f, 0, 1, 6291456LL, 3, 589824LL, 0, 0, BIGN);
    gcn_epilogue_kernel<<<dim3(24576), dim3(256), 0, stream>>>(AXW0f, XW0f, W0b, DEN, OUT0);

    // ---- weight conversions (d_out and Z tails now free) ----
    convert_planes_kernel<<<dim3(768), dim3(256), 0, stream>>>(Cw, CwP, 786432, 196608);
    pad_lw_kernel<<<dim3(2304), dim3(256), 0, stream>>>(Lw, LWPp);
    convert_qkw_kernel<<<dim3(4608), dim3(256), 0, stream>>>(Qw, Kw, QKwP);
    convert_planes_kernel<<<dim3(1152), dim3(256), 0, stream>>>(W1w, W1P, 1179648, 294912);

    // ---- phase 2: conv + linearc -> xcat planes ----
    gemm_mfma_kernel<<<dim3(12, 4, 16), dim3(256), 0, stream>>>(
        CwP, OUT0, CONVEp, Cbi, 512, 768, 1536, 1536, 0, 768,
        0, 393216LL, 393216LL, 1.f, 1, 1, 786432LL, 2, 0, 1, 6291456LL, 766);
    gemm_mfma_kernel<<<dim3(12, 64, 1), dim3(256), 0, stream>>>(
        CONVEp, LWPp, (void*)(XCATp + 768), Lb, 8192, 768, 768, 768, 768, 1536,
        0, 0, 0, 1.f, 0, 1, 6291456LL, 3, 589824LL, 1, 12582912LL, BIGN);
    copy_concat_kernel<<<dim3(24576), dim3(256), 0, stream>>>(inp, XCATp);

    // ---- phase 3: merged QK projection + scores per head ----
    for (int h = 0; h < 3; ++h) {
        gemm_mfma_kernel<<<dim3(16, 64, 1), dim3(256), 0, stream>>>(
            XCATp, QKwP + (long long)h * 1572864, QKp, QKB + h * 1024,
            8192, 1024, 1536, 1536, 1536, 1024,
            0, 0, 0, 1.f, 0, 1, 12582912LL, 3, 4718592LL, 1, 8388608LL, BIGN);
        gemm_mfma_kernel<<<dim3(6, 4, 16), dim3(256), 0, stream>>>(
            QKp, QKp + 512, P + (long long)h * 196608, nullptr,
            512, 384, 512, 1024, 1024, 384,
            524288LL, 524288LL, 589824LL, divs, 0, 1, 8388608LL, 3, 8388608LL, 0, 0, BIGN);
    }

    // ---- softmax + decisions ----
    softmax_kernel<<<dim3(24576), dim3(128), 0, stream>>>(P);
    sums1_kernel<<<dim3(768), dim3(256), 0, stream>>>(P, SUMP);
    decide2_kernel<<<dim3(1), dim3(64), 0, stream>>>(SUMP, MIDX);
    top2a_kernel<<<dim3(512), dim3(256), 0, stream>>>(P, MIDX, T2P);
    top2b_kernel<<<dim3(16), dim3(64), 0, stream>>>(T2P, THR);
    init_nnz_kernel<<<dim3(32), dim3(256), 0, stream>>>(CNT, NNZC, DEN2);
    scan_thr_kernel<<<dim3(192), dim3(256), 0, stream>>>(P, MIDX, THR, CNT, POS);
    build_nnz_kernel<<<dim3(1), dim3(64), 0, stream>>>(CNT, POS, NNZC, NNZJ, NNZV, DEN2);

    // ---- phase 5: GCN layer 1 (sparse adj2) + fc ----
    gemm_mfma_kernel<<<dim3(12, 64, 1), dim3(256), 0, stream>>>(
        XCATp, W1P, XW1f, nullptr, 8192, 768, 1536, 1536, 1536, 768,
        0, 0, 0, 1.f, 0, 1, 12582912LL, 3, 1179648LL, 0, 0, BIGN);
    convert_planes_kernel<<<dim3(576), dim3(256), 0, stream>>>(F1, F1P, 589824, 147456);
    convert_planes_kernel<<<dim3(576), dim3(256), 0, stream>>>(F2, F2P, 589824, 147456);
    gcn1_epilogue_kernel<<<dim3(8192), dim3(256), 0, stream>>>(XW1f, W1b, DEN2, NNZC, NNZJ, NNZV, OUTL1p);
    gemm_mfma_kernel<<<dim3(12, 64, 1), dim3(256), 0, stream>>>(
        OUTL1p, F1P, H1p, nullptr, 8192, 768, 768, 768, 768, 768,
        0, 0, 0, 1.f, 1, 1, 6291456LL, 3, 589824LL, 1, 6291456LL, BIGN);
    gemm_mfma_kernel<<<dim3(12, 64, 1), dim3(256), 0, stream>>>(
        H1p, F2P, out, nullptr, 8192, 768, 768, 768, 768, 768,
        0, 0, 0, 1.f, 0, 1, 6291456LL, 3, 589824LL, 0, 0, BIGN);
}